// Round 1
// baseline (1011.309 us; speedup 1.0000x reference)
//
#include <hip/hip_runtime.h>
#include <math.h>

#define B_    16
#define CIN_  128
#define COUT_ 256
#define H_    64
#define W_    64
#define HW_   4096

// workspace layout (float offsets)
#define WS_G       0        // 2048
#define WS_RW      2048     // 64
#define WS_P       2112     // 4096
#define WS_CA      6208     // 4096
#define WS_PSUM    10304    // 4096
#define WS_PSQ     14400    // 4096
#define WS_BNSCALE 18496    // 256
#define WS_BNSHIFT 18752    // 256
#define WS_SA      19456    // 65536
#define WS_WCOMB   84992    // 16*128*9*256 = 4718592

// --- K1/K5: global average pool over one [HW] plane per block ---
__global__ void k_gap(const float* __restrict__ x, float* __restrict__ g) {
    int bc = blockIdx.x;
    const float4* p4 = (const float4*)(x + (size_t)bc * HW_);
    float s = 0.f;
    for (int i = threadIdx.x; i < HW_/4; i += 256) {
        float4 v = p4[i];
        s += v.x + v.y + v.z + v.w;
    }
    for (int o = 32; o > 0; o >>= 1) s += __shfl_down(s, o, 64);
    __shared__ float ls[4];
    int wid = threadIdx.x >> 6, lane = threadIdx.x & 63;
    if (lane == 0) ls[wid] = s;
    __syncthreads();
    if (threadIdx.x == 0) g[bc] = (ls[0]+ls[1]+ls[2]+ls[3]) * (1.f/(float)HW_);
}

// --- K2: routing MLP + softmax (1 block, thread b handles batch b) ---
__global__ void k_route(const float* __restrict__ g,
                        const float* r1w, const float* r1b,
                        const float* r2w, const float* r2b,
                        const float* r3w, const float* r3b,
                        float* __restrict__ rw) {
    int b = threadIdx.x;
    if (b >= B_) return;
    const float* gb = g + b * CIN_;
    float h[2];
    for (int j = 0; j < 2; ++j) {
        float s = r1b[j];
        for (int c = 0; c < CIN_; ++c) s += gb[c] * r1w[j*CIN_ + c];
        h[j] = fmaxf(s, 0.f);
    }
    float h2[4];
    for (int e = 0; e < 4; ++e)
        h2[e] = fmaxf(r2b[e] + h[0]*r2w[e*2] + h[1]*r2w[e*2+1], 0.f);
    float lg[4]; float m = -1e30f;
    for (int e = 0; e < 4; ++e) {
        float s = r3b[e];
        for (int j = 0; j < 4; ++j) s += h2[j]*r3w[e*4+j];
        lg[e] = s; m = fmaxf(m, s);
    }
    float den = 0.f;
    for (int e = 0; e < 4; ++e) { lg[e] = expf(lg[e]-m); den += lg[e]; }
    float inv = 1.f/den;
    for (int e = 0; e < 4; ++e) rw[b*4+e] = lg[e]*inv;
}

// --- K3: combine expert weights per batch into [b][ci][j][co] layout ---
__global__ void k_wcomb(const float* __restrict__ ew, const float* __restrict__ rw,
                        float* __restrict__ wc) {
    int id = blockIdx.x * 256 + threadIdx.x;   // total 4718592, grid exact
    int co = id & 255;
    int j  = (id >> 8) % 9;
    int ci = (id / 2304) & 127;
    int b  = id / (CIN_*9*COUT_);
    const float* rwb = rw + b*4;
    float s = 0.f;
    #pragma unroll
    for (int e = 0; e < 4; ++e)
        s += rwb[e] * ew[(((size_t)e*COUT_ + co)*CIN_ + ci)*9 + j];
    wc[id] = s;
}

// --- K4: direct 3x3 conv, per-batch combined weights ---
// block: 32 co x (2 rows x 64 cols); thread: 4 co x 4 px
__global__ __launch_bounds__(256) void k_conv(const float* __restrict__ x,
                                              const float* __restrict__ wc,
                                              float* __restrict__ out) {
    __shared__ float xs[8][4][66];   // [ci][row][padded col]
    __shared__ float wl[8][9][32];   // [ci][tap][co]
    int ht = blockIdx.x;       // 0..31 (2 rows each)
    int cb = blockIdx.y;       // 0..7  (32 co each)
    int b  = blockIdx.z;
    int t  = threadIdx.x;
    int h0 = ht*2;
    int pxg = t & 31;
    int hr  = pxg >> 4;          // 0..1
    int w0  = (pxg & 15) * 4;    // 0..60
    int co0 = (t >> 5) * 4;      // 0..28
    float acc[4][4] = {{0.f}};
    const float* xb = x  + (size_t)b * CIN_ * HW_;
    const float* wb = wc + (size_t)b * CIN_ * 9 * COUT_;

    for (int ci0 = 0; ci0 < CIN_; ci0 += 8) {
        // stage x rows h0-1..h0+2 for 8 channels, zero-padded
        #pragma unroll
        for (int q = 0; q < 2; ++q) {
            int slot = t + q*256;          // 0..511
            int row_id = slot >> 4;        // 0..31
            int ci = row_id >> 2, r = row_id & 3;
            int col4 = (slot & 15) * 4;
            int grow = h0 - 1 + r;
            float4 v = make_float4(0.f,0.f,0.f,0.f);
            if (grow >= 0 && grow < H_)
                v = *(const float4*)(xb + (size_t)(ci0+ci)*HW_ + grow*W_ + col4);
            xs[ci][r][1+col4] = v.x; xs[ci][r][2+col4] = v.y;
            xs[ci][r][3+col4] = v.z; xs[ci][r][4+col4] = v.w;
        }
        if (t < 32) { int ci = t >> 2, r = t & 3; xs[ci][r][0] = 0.f; xs[ci][r][65] = 0.f; }
        // stage weights (coalesced: 32 consecutive co per (ci,j))
        #pragma unroll
        for (int q = 0; q < 9; ++q) {
            int l = t + q*256;             // 0..2303
            int col = l & 31, j = (l >> 5) % 9, ci = l / 288;
            wl[ci][j][col] = wb[(size_t)(ci0+ci)*9*COUT_ + j*COUT_ + cb*32 + col];
        }
        __syncthreads();

        #pragma unroll
        for (int ci = 0; ci < 8; ++ci) {
            float xv[3][6];
            #pragma unroll
            for (int d = 0; d < 3; ++d)
                #pragma unroll
                for (int k = 0; k < 6; ++k)
                    xv[d][k] = xs[ci][hr+d][w0+k];
            #pragma unroll
            for (int dh = 0; dh < 3; ++dh)
              #pragma unroll
              for (int dw = 0; dw < 3; ++dw) {
                float4 wv = *(const float4*)&wl[ci][dh*3+dw][co0];
                #pragma unroll
                for (int q = 0; q < 4; ++q) {
                    acc[0][q] = fmaf(wv.x, xv[dh][q+dw], acc[0][q]);
                    acc[1][q] = fmaf(wv.y, xv[dh][q+dw], acc[1][q]);
                    acc[2][q] = fmaf(wv.z, xv[dh][q+dw], acc[2][q]);
                    acc[3][q] = fmaf(wv.w, xv[dh][q+dw], acc[3][q]);
                }
              }
        }
        __syncthreads();
    }
    float* ob = out + (size_t)b * COUT_ * HW_;
    #pragma unroll
    for (int c = 0; c < 4; ++c) {
        int co = cb*32 + co0 + c;
        float4 v = make_float4(acc[c][0], acc[c][1], acc[c][2], acc[c][3]);
        *(float4*)(ob + (size_t)co*HW_ + (h0+hr)*W_ + w0) = v;
    }
}

// --- K6: SE channel attention ---
__global__ void k_ca(const float* __restrict__ p, const float* ca1w, const float* ca1b,
                     const float* ca2w, const float* ca2b, float* __restrict__ ca) {
    int b = blockIdx.x;
    __shared__ float h1[64];
    int t = threadIdx.x;   // 64 threads
    const float* pb = p + b*COUT_;
    float s = ca1b[t];
    for (int c = 0; c < COUT_; ++c) s += pb[c] * ca1w[t*COUT_ + c];
    h1[t] = fmaxf(s, 0.f);
    __syncthreads();
    for (int i = 0; i < 4; ++i) {
        int co = t*4 + i;
        float s2 = ca2b[co];
        for (int j = 0; j < 64; ++j) s2 += h1[j] * ca2w[co*64 + j];
        ca[b*COUT_ + co] = 1.f/(1.f + expf(-s2));
    }
}

// --- K7: spatial attention: 7x7 conv over 256 channels -> sigmoid ---
__global__ __launch_bounds__(256) void k_sa(const float* __restrict__ mix,
                                            const float* __restrict__ saw,
                                            const float* __restrict__ sab,
                                            float* __restrict__ sa) {
    int tile = blockIdx.x;     // 0..15 (4x4 of 16x16 tiles)
    int b = blockIdx.y;
    int h0 = (tile >> 2) * 16, w0 = (tile & 3) * 16;
    int t = threadIdx.x;
    int ty = t >> 4, tx = t & 15;
    __shared__ float ts[4][22][22];
    __shared__ float wv[4][49];
    float acc = 0.f;
    const float* mb = mix + (size_t)b * COUT_ * HW_;
    for (int c0 = 0; c0 < COUT_; c0 += 4) {
        for (int i = t; i < 4*22*22; i += 256) {
            int c = i / 484, rem = i % 484, r = rem / 22, col = rem % 22;
            int gr = h0 - 3 + r, gc = w0 - 3 + col;
            float v = 0.f;
            if (gr >= 0 && gr < H_ && gc >= 0 && gc < W_)
                v = mb[(size_t)(c0+c)*HW_ + gr*W_ + gc];
            ts[c][r][col] = v;
        }
        for (int i = t; i < 4*49; i += 256)
            wv[i/49][i%49] = saw[(c0 + i/49)*49 + i%49];
        __syncthreads();
        #pragma unroll
        for (int c = 0; c < 4; ++c)
            for (int dh = 0; dh < 7; ++dh)
                #pragma unroll
                for (int dw = 0; dw < 7; ++dw)
                    acc = fmaf(ts[c][ty+dh][tx+dw], wv[c][dh*7+dw], acc);
        __syncthreads();
    }
    sa[(size_t)b*HW_ + (h0+ty)*W_ + (w0+tx)] = 1.f/(1.f + expf(-(acc + sab[0])));
}

// --- K8: out = mix*ca*sa (in place) + per-(b,c) partial sums for BN ---
__global__ void k_scale_stats(float* __restrict__ io, const float* __restrict__ ca,
                              const float* __restrict__ sa,
                              float* __restrict__ psum, float* __restrict__ psq) {
    int c = blockIdx.x & 255;
    int b = blockIdx.x >> 8;
    float cav = ca[b*COUT_ + c];
    float* pl = io + ((size_t)b*COUT_ + c) * HW_;
    const float* sab = sa + (size_t)b * HW_;
    float s = 0.f, sq = 0.f;
    for (int i = threadIdx.x; i < HW_/4; i += 256) {
        float4 v = ((float4*)pl)[i];
        float4 w = ((const float4*)sab)[i];
        v.x *= cav*w.x; v.y *= cav*w.y; v.z *= cav*w.z; v.w *= cav*w.w;
        ((float4*)pl)[i] = v;
        s  += v.x+v.y+v.z+v.w;
        sq += v.x*v.x+v.y*v.y+v.z*v.z+v.w*v.w;
    }
    for (int o = 32; o > 0; o >>= 1) { s += __shfl_down(s,o,64); sq += __shfl_down(sq,o,64); }
    __shared__ float ls[8];
    int wid = threadIdx.x>>6, lane = threadIdx.x&63;
    if (lane==0) { ls[wid]=s; ls[4+wid]=sq; }
    __syncthreads();
    if (threadIdx.x==0) {
        psum[b*COUT_+c] = ls[0]+ls[1]+ls[2]+ls[3];
        psq [b*COUT_+c] = ls[4]+ls[5]+ls[6]+ls[7];
    }
}

// --- K9: finalize BN scale/shift (deterministic reduce over b) ---
__global__ void k_bnfin(const float* __restrict__ psum, const float* __restrict__ psq,
                        const float* __restrict__ gamma, const float* __restrict__ beta,
                        float* __restrict__ scale, float* __restrict__ shift) {
    int c = threadIdx.x; // 256
    float s=0.f, q=0.f;
    for (int b = 0; b < B_; ++b) { s += psum[b*COUT_+c]; q += psq[b*COUT_+c]; }
    float n = (float)(B_*HW_);
    float mean = s/n;
    float var = q/n - mean*mean;
    float sc = gamma[c] * rsqrtf(var + 1e-5f);
    scale[c] = sc;
    shift[c] = beta[c] - mean*sc;
}

// --- K10: apply BN + ReLU in place ---
__global__ void k_bnapply(float* __restrict__ io, const float* __restrict__ scale,
                          const float* __restrict__ shift) {
    size_t i = (size_t)blockIdx.x * 256 + threadIdx.x;  // float4 index, 4194304 total
    int c = (int)((i >> 10) & 255);
    float4 v = ((float4*)io)[i];
    float sc = scale[c], sh = shift[c];
    v.x = fmaxf(fmaf(v.x,sc,sh), 0.f); v.y = fmaxf(fmaf(v.y,sc,sh), 0.f);
    v.z = fmaxf(fmaf(v.z,sc,sh), 0.f); v.w = fmaxf(fmaf(v.w,sc,sh), 0.f);
    ((float4*)io)[i] = v;
}

extern "C" void kernel_launch(void* const* d_in, const int* in_sizes, int n_in,
                              void* d_out, int out_size, void* d_ws, size_t ws_size,
                              hipStream_t stream) {
    const float* x    = (const float*)d_in[0];
    const float* ew   = (const float*)d_in[1];
    const float* r1w  = (const float*)d_in[2];
    const float* r1b  = (const float*)d_in[3];
    const float* r2w  = (const float*)d_in[4];
    const float* r2b  = (const float*)d_in[5];
    const float* r3w  = (const float*)d_in[6];
    const float* r3b  = (const float*)d_in[7];
    const float* ca1w = (const float*)d_in[8];
    const float* ca1b = (const float*)d_in[9];
    const float* ca2w = (const float*)d_in[10];
    const float* ca2b = (const float*)d_in[11];
    const float* saw  = (const float*)d_in[12];
    const float* sab  = (const float*)d_in[13];
    const float* gm   = (const float*)d_in[14];
    const float* bt   = (const float*)d_in[15];
    float* out = (float*)d_out;
    float* ws  = (float*)d_ws;

    k_gap<<<B_*CIN_, 256, 0, stream>>>(x, ws+WS_G);
    k_route<<<1, 64, 0, stream>>>(ws+WS_G, r1w, r1b, r2w, r2b, r3w, r3b, ws+WS_RW);
    k_wcomb<<<18432, 256, 0, stream>>>(ew, ws+WS_RW, ws+WS_WCOMB);
    k_conv<<<dim3(32,8,16), 256, 0, stream>>>(x, ws+WS_WCOMB, out);
    k_gap<<<B_*COUT_, 256, 0, stream>>>(out, ws+WS_P);
    k_ca<<<B_, 64, 0, stream>>>(ws+WS_P, ca1w, ca1b, ca2w, ca2b, ws+WS_CA);
    k_sa<<<dim3(16,B_), 256, 0, stream>>>(out, saw, sab, ws+WS_SA);
    k_scale_stats<<<B_*COUT_, 256, 0, stream>>>(out, ws+WS_CA, ws+WS_SA, ws+WS_PSUM, ws+WS_PSQ);
    k_bnfin<<<1, 256, 0, stream>>>(ws+WS_PSUM, ws+WS_PSQ, gm, bt, ws+WS_BNSCALE, ws+WS_BNSHIFT);
    k_bnapply<<<16384, 256, 0, stream>>>(out, ws+WS_BNSCALE, ws+WS_BNSHIFT);
}

// Round 2
// 291.770 us; speedup vs baseline: 3.4661x; 3.4661x over previous
//
#include <hip/hip_runtime.h>
#include <math.h>

#define B_    16
#define CIN_  128
#define COUT_ 256
#define H_    64
#define W_    64
#define HW_   4096

typedef __attribute__((ext_vector_type(8))) short short8v;
typedef __attribute__((ext_vector_type(4))) float f32x4;

// workspace layout (float offsets)
#define WS_G       0
#define WS_RW      2048
#define WS_P       2112
#define WS_CA      6208
#define WS_PSUM    10304
#define WS_PSQ     14400
#define WS_BNSCALE 18496
#define WS_BNSHIFT 18752
#define WS_SA      19456      // 65536
#define WS_PART    84992      // 16*16*4096 = 1048576
#define WS_WCB_F   1133568    // bf16 [16][9][256][128] = 4718592 bf16 = 2359296 floats
#define WS_XT_F    3492864    // bf16 [16][66][66][128] = 8921088 bf16
#define XT_BYTES   17842176

static __device__ __forceinline__ unsigned short f2bf(float f) {
    union { float f; unsigned int u; } v; v.f = f;
    unsigned int u = v.u;
    return (unsigned short)((u + 0x7FFFu + ((u >> 16) & 1u)) >> 16);  // RTNE
}

__device__ __forceinline__ void gl16(const void* g, const void* l) {
    __builtin_amdgcn_global_load_lds(
        (const __attribute__((address_space(1))) unsigned int*)g,
        (__attribute__((address_space(3))) unsigned int*)l, 16, 0, 0);
}

// --- GAP over one [HW] plane per block ---
__global__ void k_gap(const float* __restrict__ x, float* __restrict__ g) {
    int bc = blockIdx.x;
    const float4* p4 = (const float4*)(x + (size_t)bc * HW_);
    float s = 0.f;
    for (int i = threadIdx.x; i < HW_/4; i += 256) {
        float4 v = p4[i];
        s += v.x + v.y + v.z + v.w;
    }
    for (int o = 32; o > 0; o >>= 1) s += __shfl_down(s, o, 64);
    __shared__ float ls[4];
    int wid = threadIdx.x >> 6, lane = threadIdx.x & 63;
    if (lane == 0) ls[wid] = s;
    __syncthreads();
    if (threadIdx.x == 0) g[bc] = (ls[0]+ls[1]+ls[2]+ls[3]) * (1.f/(float)HW_);
}

// --- routing MLP + softmax ---
__global__ void k_route(const float* __restrict__ g,
                        const float* r1w, const float* r1b,
                        const float* r2w, const float* r2b,
                        const float* r3w, const float* r3b,
                        float* __restrict__ rw) {
    int b = threadIdx.x;
    if (b >= B_) return;
    const float* gb = g + b * CIN_;
    float h[2];
    for (int j = 0; j < 2; ++j) {
        float s = r1b[j];
        for (int c = 0; c < CIN_; ++c) s += gb[c] * r1w[j*CIN_ + c];
        h[j] = fmaxf(s, 0.f);
    }
    float h2[4];
    for (int e = 0; e < 4; ++e)
        h2[e] = fmaxf(r2b[e] + h[0]*r2w[e*2] + h[1]*r2w[e*2+1], 0.f);
    float lg[4]; float m = -1e30f;
    for (int e = 0; e < 4; ++e) {
        float s = r3b[e];
        for (int j = 0; j < 4; ++j) s += h2[j]*r3w[e*4+j];
        lg[e] = s; m = fmaxf(m, s);
    }
    float den = 0.f;
    for (int e = 0; e < 4; ++e) { lg[e] = expf(lg[e]-m); den += lg[e]; }
    float inv = 1.f/den;
    for (int e = 0; e < 4; ++e) rw[b*4+e] = lg[e]*inv;
}

// --- x -> padded channels-last bf16: x_t[b][h+1][w+1][ci] ---
__global__ __launch_bounds__(256) void k_xt(const float* __restrict__ x,
                                            unsigned short* __restrict__ xt) {
    int h = blockIdx.x, b = blockIdx.y;
    int t = threadIdx.x;
    int w = t & 63, c8 = t >> 6;          // c8: 0..3
    unsigned short* orow = xt + (((size_t)b*66 + h + 1)*66 + (w + 1)) * 128;
    #pragma unroll
    for (int i = 0; i < 4; ++i) {
        int ci0 = i*32 + c8*8;
        short8v vv;
        #pragma unroll
        for (int j = 0; j < 8; ++j) {
            float f = x[(((size_t)b*CIN_ + ci0 + j)*H_ + h)*W_ + w];
            vv[j] = (short)f2bf(f);
        }
        *(short8v*)(orow + ci0) = vv;
    }
}

// --- combined expert weights -> bf16 [b][tap][co][ci] ---
__global__ __launch_bounds__(256) void k_wcomb(const float* __restrict__ ew,
                                               const float* __restrict__ rw,
                                               unsigned short* __restrict__ wc) {
    int co = blockIdx.x;
    int t = threadIdx.x;
    __shared__ float ewl[4*1152];
    __shared__ float rwl[64];
    #pragma unroll
    for (int e = 0; e < 4; ++e) {
        const float* src = ew + ((size_t)(e*COUT_ + co))*1152;
        for (int i = t; i < 1152; i += 256) ewl[e*1152 + i] = src[i];
    }
    if (t < 64) rwl[t] = rw[t];
    __syncthreads();
    for (int i = 0; i < 72; ++i) {
        int f = i*256 + t;
        int b = f / 1152;
        int rem = f - b*1152;
        int tap = rem >> 7, ci = rem & 127;
        int lidx = ci*9 + tap;
        float v = rwl[b*4+0]*ewl[0*1152+lidx] + rwl[b*4+1]*ewl[1*1152+lidx]
                + rwl[b*4+2]*ewl[2*1152+lidx] + rwl[b*4+3]*ewl[3*1152+lidx];
        wc[((size_t)(b*9 + tap)*COUT_ + co)*128 + ci] = f2bf(v);
    }
}

// --- MFMA implicit-GEMM conv: block = 64co x (4 rows x 64 cols) ---
__global__ __launch_bounds__(256) void k_conv(const unsigned short* __restrict__ xt,
                                              const unsigned short* __restrict__ wc,
                                              float* __restrict__ out) {
    __shared__ unsigned short xs[1600*8];   // 25.6 KB: [6 rows][66 cols][32 ci] + pad
    __shared__ unsigned short wl[2304*8];   // 36.9 KB: [9 tap][64 co][32 ci]
    int ht = blockIdx.x;            // 0..15 -> h0 = 4*ht
    int cb = blockIdx.y;            // 0..3  -> co base 64*cb
    int b  = blockIdx.z;
    int t  = threadIdx.x;
    int wv = t >> 6, lane = t & 63;
    int lr = lane & 15, kq = lane >> 4;
    int h0 = ht * 4;

    const unsigned short* xtb = xt + (size_t)b * 66*66*128;
    const unsigned short* wcb = wc + (size_t)b * 9*256*128;

    f32x4 acc[4][4];
    #pragma unroll
    for (int m = 0; m < 4; ++m)
        #pragma unroll
        for (int n = 0; n < 4; ++n) acc[m][n] = (f32x4){0.f,0.f,0.f,0.f};

    for (int ci0 = 0; ci0 < CIN_; ci0 += 32) {
        __syncthreads();   // previous compute done before overwrite
        // stage x tile: 1584 slots of 16B (+pad to 1600), 25 wave-instrs
        for (int j = wv; j < 25; j += 4) {
            int s = j*64 + lane;
            if (s > 1583) s = 1583;
            int pos = s >> 2, q = s & 3;
            int rp = pos / 66, cp = pos - rp*66;
            const unsigned short* g = xtb + (((size_t)(h0 + rp)*66 + cp)*128 + ci0 + q*8);
            gl16(g, (const char*)xs + (size_t)j*1024);
        }
        // stage weights: 2304 slots, 36 wave-instrs
        for (int j = wv; j < 36; j += 4) {
            int s = j*64 + lane;
            int tap = s >> 8, col = (s >> 2) & 63, q = s & 3;
            const unsigned short* g = wcb + (((size_t)tap*COUT_ + cb*64 + col)*128 + ci0 + q*8);
            gl16(g, (const char*)wl + (size_t)j*1024);
        }
        asm volatile("s_waitcnt vmcnt(0)" ::: "memory");
        __syncthreads();

        #pragma unroll
        for (int dh = 0; dh < 3; ++dh) {
            #pragma unroll
            for (int dw = 0; dw < 3; ++dw) {
                int tap = dh*3 + dw;
                short8v af[4], bfv[4];
                #pragma unroll
                for (int m = 0; m < 4; ++m)
                    af[m] = *(const short8v*)(wl + ((size_t)tap*2048 + (m*16 + lr)*32 + kq*8));
                #pragma unroll
                for (int n = 0; n < 4; ++n)
                    bfv[n] = *(const short8v*)(xs + ((size_t)(wv+dh)*2112 + (n*16 + lr + dw)*32 + kq*8));
                #pragma unroll
                for (int m = 0; m < 4; ++m)
                    #pragma unroll
                    for (int n = 0; n < 4; ++n)
                        acc[m][n] = __builtin_amdgcn_mfma_f32_16x16x32_bf16(
                            af[m], bfv[n], acc[m][n], 0, 0, 0);
            }
        }
    }

    float* ob = out + ((size_t)b*COUT_ + cb*64)*HW_ + (h0 + wv)*W_;
    #pragma unroll
    for (int m = 0; m < 4; ++m)
        #pragma unroll
        for (int n = 0; n < 4; ++n) {
            f32x4 v = acc[m][n];
            #pragma unroll
            for (int r = 0; r < 4; ++r)
                ob[(size_t)(m*16 + kq*4 + r)*HW_ + n*16 + lr] = v[r];
        }
}

// --- SE channel attention ---
__global__ void k_ca(const float* __restrict__ p, const float* ca1w, const float* ca1b,
                     const float* ca2w, const float* ca2b, float* __restrict__ ca) {
    int b = blockIdx.x;
    __shared__ float h1[64];
    int t = threadIdx.x;   // 64
    const float* pb = p + b*COUT_;
    float s = ca1b[t];
    for (int c = 0; c < COUT_; ++c) s += pb[c] * ca1w[t*COUT_ + c];
    h1[t] = fmaxf(s, 0.f);
    __syncthreads();
    for (int i = 0; i < 4; ++i) {
        int co = t*4 + i;
        float s2 = ca2b[co];
        for (int j = 0; j < 64; ++j) s2 += h1[j] * ca2w[co*64 + j];
        ca[b*COUT_ + co] = 1.f/(1.f + expf(-s2));
    }
}

// --- spatial attention partials: 16 channels per block ---
__global__ __launch_bounds__(256) void k_sa(const float* __restrict__ mix,
                                            const float* __restrict__ saw,
                                            float* __restrict__ part) {
    int cgrp = blockIdx.x;   // 0..15
    int b    = blockIdx.y;   // 0..15
    int t = threadIdx.x;
    __shared__ float ts[2][70][76];
    int col4 = (t & 15) * 4;
    int r0   = (t >> 4) * 4;
    float acc[4][4];
    #pragma unroll
    for (int k = 0; k < 4; ++k)
        #pragma unroll
        for (int j = 0; j < 4; ++j) acc[k][j] = 0.f;

    for (int pr = 0; pr < 8; ++pr) {
        __syncthreads();
        // stage 2 channels with 3-halo, zero-padded
        for (int id = t; id < 2*4900; id += 256) {
            int ch = id / 4900, rem = id - ch*4900;
            int r = rem / 70, col = rem - r*70;
            int c = cgrp*16 + pr*2 + ch;
            int gr = r - 3, gc = col - 3;
            float v = 0.f;
            if (gr >= 0 && gr < H_ && gc >= 0 && gc < W_)
                v = mix[(((size_t)b*COUT_ + c)*H_ + gr)*W_ + gc];
            ts[ch][r][col] = v;
        }
        __syncthreads();
        #pragma unroll
        for (int ch = 0; ch < 2; ++ch) {
            const float* wp = saw + (cgrp*16 + pr*2 + ch)*49;  // uniform -> SGPR
            #pragma unroll
            for (int ir = 0; ir < 10; ++ir) {
                float win[12];
                float4 aa = *(const float4*)&ts[ch][r0+ir][col4];
                float4 bb = *(const float4*)&ts[ch][r0+ir][col4+4];
                float4 cc = *(const float4*)&ts[ch][r0+ir][col4+8];
                win[0]=aa.x; win[1]=aa.y; win[2]=aa.z; win[3]=aa.w;
                win[4]=bb.x; win[5]=bb.y; win[6]=bb.z; win[7]=bb.w;
                win[8]=cc.x; win[9]=cc.y; win[10]=cc.z; win[11]=cc.w;
                #pragma unroll
                for (int dh = 0; dh < 7; ++dh) {
                    int k = ir - dh;
                    if (k >= 0 && k < 4) {
                        #pragma unroll
                        for (int dw = 0; dw < 7; ++dw) {
                            float wgt = wp[dh*7 + dw];
                            #pragma unroll
                            for (int j = 0; j < 4; ++j)
                                acc[k][j] = fmaf(wgt, win[j + dw], acc[k][j]);
                        }
                    }
                }
            }
        }
    }
    float* pb = part + ((size_t)b*16 + cgrp)*HW_;
    #pragma unroll
    for (int k = 0; k < 4; ++k) {
        float4 v = make_float4(acc[k][0], acc[k][1], acc[k][2], acc[k][3]);
        *(float4*)(pb + (r0 + k)*W_ + col4) = v;
    }
}

// --- reduce SA partials + sigmoid ---
__global__ void k_sared(const float* __restrict__ part, const float* __restrict__ sab,
                        float* __restrict__ sa) {
    int g = blockIdx.x*256 + threadIdx.x;   // 65536
    int b = g >> 12, p = g & 4095;
    float s = sab[0];
    #pragma unroll
    for (int cg = 0; cg < 16; ++cg) s += part[((size_t)b*16 + cg)*HW_ + p];
    sa[g] = 1.f/(1.f + expf(-s));
}

// --- out = mix*ca*sa (in place) + per-(b,c) partial sums for BN ---
__global__ void k_scale_stats(float* __restrict__ io, const float* __restrict__ ca,
                              const float* __restrict__ sa,
                              float* __restrict__ psum, float* __restrict__ psq) {
    int c = blockIdx.x & 255;
    int b = blockIdx.x >> 8;
    float cav = ca[b*COUT_ + c];
    float* pl = io + ((size_t)b*COUT_ + c) * HW_;
    const float* sab = sa + (size_t)b * HW_;
    float s = 0.f, sq = 0.f;
    for (int i = threadIdx.x; i < HW_/4; i += 256) {
        float4 v = ((float4*)pl)[i];
        float4 w = ((const float4*)sab)[i];
        v.x *= cav*w.x; v.y *= cav*w.y; v.z *= cav*w.z; v.w *= cav*w.w;
        ((float4*)pl)[i] = v;
        s  += v.x+v.y+v.z+v.w;
        sq += v.x*v.x+v.y*v.y+v.z*v.z+v.w*v.w;
    }
    for (int o = 32; o > 0; o >>= 1) { s += __shfl_down(s,o,64); sq += __shfl_down(sq,o,64); }
    __shared__ float ls[8];
    int wid = threadIdx.x>>6, lane = threadIdx.x&63;
    if (lane==0) { ls[wid]=s; ls[4+wid]=sq; }
    __syncthreads();
    if (threadIdx.x==0) {
        psum[b*COUT_+c] = ls[0]+ls[1]+ls[2]+ls[3];
        psq [b*COUT_+c] = ls[4]+ls[5]+ls[6]+ls[7];
    }
}

// --- finalize BN scale/shift ---
__global__ void k_bnfin(const float* __restrict__ psum, const float* __restrict__ psq,
                        const float* __restrict__ gamma, const float* __restrict__ beta,
                        float* __restrict__ scale, float* __restrict__ shift) {
    int c = threadIdx.x; // 256
    float s=0.f, q=0.f;
    for (int b = 0; b < B_; ++b) { s += psum[b*COUT_+c]; q += psq[b*COUT_+c]; }
    float n = (float)(B_*HW_);
    float mean = s/n;
    float var = q/n - mean*mean;
    float sc = gamma[c] * rsqrtf(var + 1e-5f);
    scale[c] = sc;
    shift[c] = beta[c] - mean*sc;
}

// --- BN + ReLU in place ---
__global__ void k_bnapply(float* __restrict__ io, const float* __restrict__ scale,
                          const float* __restrict__ shift) {
    size_t i = (size_t)blockIdx.x * 256 + threadIdx.x;
    int c = (int)((i >> 10) & 255);
    float4 v = ((float4*)io)[i];
    float sc = scale[c], sh = shift[c];
    v.x = fmaxf(fmaf(v.x,sc,sh), 0.f); v.y = fmaxf(fmaf(v.y,sc,sh), 0.f);
    v.z = fmaxf(fmaf(v.z,sc,sh), 0.f); v.w = fmaxf(fmaf(v.w,sc,sh), 0.f);
    ((float4*)io)[i] = v;
}

extern "C" void kernel_launch(void* const* d_in, const int* in_sizes, int n_in,
                              void* d_out, int out_size, void* d_ws, size_t ws_size,
                              hipStream_t stream) {
    const float* x    = (const float*)d_in[0];
    const float* ew   = (const float*)d_in[1];
    const float* r1w  = (const float*)d_in[2];
    const float* r1b  = (const float*)d_in[3];
    const float* r2w  = (const float*)d_in[4];
    const float* r2b  = (const float*)d_in[5];
    const float* r3w  = (const float*)d_in[6];
    const float* r3b  = (const float*)d_in[7];
    const float* ca1w = (const float*)d_in[8];
    const float* ca1b = (const float*)d_in[9];
    const float* ca2w = (const float*)d_in[10];
    const float* ca2b = (const float*)d_in[11];
    const float* saw  = (const float*)d_in[12];
    const float* sab  = (const float*)d_in[13];
    const float* gm   = (const float*)d_in[14];
    const float* bt   = (const float*)d_in[15];
    float* out = (float*)d_out;
    float* ws  = (float*)d_ws;
    unsigned short* wcb = (unsigned short*)(ws + WS_WCB_F);
    unsigned short* xt  = (unsigned short*)(ws + WS_XT_F);

    hipMemsetAsync((void*)xt, 0, XT_BYTES, stream);
    k_xt<<<dim3(64,16), 256, 0, stream>>>(x, xt);
    k_gap<<<B_*CIN_, 256, 0, stream>>>(x, ws+WS_G);
    k_route<<<1, 64, 0, stream>>>(ws+WS_G, r1w, r1b, r2w, r2b, r3w, r3b, ws+WS_RW);
    k_wcomb<<<COUT_, 256, 0, stream>>>(ew, ws+WS_RW, wcb);
    k_conv<<<dim3(16,4,16), 256, 0, stream>>>(xt, wcb, out);
    k_gap<<<B_*COUT_, 256, 0, stream>>>(out, ws+WS_P);
    k_ca<<<B_, 64, 0, stream>>>(ws+WS_P, ca1w, ca1b, ca2w, ca2b, ws+WS_CA);
    k_sa<<<dim3(16,16), 256, 0, stream>>>(out, saw, ws+WS_PART);
    k_sared<<<256, 256, 0, stream>>>(ws+WS_PART, sab, ws+WS_SA);
    k_scale_stats<<<B_*COUT_, 256, 0, stream>>>(out, ws+WS_CA, ws+WS_SA, ws+WS_PSUM, ws+WS_PSQ);
    k_bnfin<<<1, 256, 0, stream>>>(ws+WS_PSUM, ws+WS_PSQ, gm, bt, ws+WS_BNSCALE, ws+WS_BNSHIFT);
    k_bnapply<<<16384, 256, 0, stream>>>(out, ws+WS_BNSCALE, ws+WS_BNSHIFT);
}

// Round 4
// 194.729 us; speedup vs baseline: 5.1934x; 1.4983x over previous
//
#include <hip/hip_runtime.h>
#include <math.h>

#define B_    16
#define CIN_  128
#define COUT_ 256
#define H_    64
#define W_    64
#define HW_   4096

typedef __attribute__((ext_vector_type(8))) short short8v;
typedef __attribute__((ext_vector_type(4))) float f32x4;

// workspace layout (float offsets)
#define WS_G       0
#define WS_RW      2048
#define WS_P       2112
#define WS_CA      6208
#define WS_PSUM    10304
#define WS_PSQ     14400
#define WS_BNSCALE 18496
#define WS_BNSHIFT 18752
#define WS_SA      19456      // 65536
#define WS_WSA     84992      // 16384 bf16 = 8192 floats
#define WS_WCB_F   1133568    // bf16 [16][9][256][128] = 4718592 bf16 = 2359296 floats
#define WS_XT_F    3492864    // bf16 [16][66][66][128] = 8921088 bf16 (REUSED as u after conv)
#define XT_BYTES   17842176
#define WS_U_F     WS_XT_F    // fp32 [16][64][4096] = 4194304 floats (fits in xt region)

static __device__ __forceinline__ unsigned short f2bf(float f) {
    union { float f; unsigned int u; } v; v.f = f;
    unsigned int u = v.u;
    return (unsigned short)((u + 0x7FFFu + ((u >> 16) & 1u)) >> 16);  // RTNE
}

__device__ __forceinline__ void gl16(const void* g, const void* l) {
    __builtin_amdgcn_global_load_lds(
        (const __attribute__((address_space(1))) unsigned int*)g,
        (__attribute__((address_space(3))) unsigned int*)l, 16, 0, 0);
}

// --- GAP over one [HW] plane per block ---
__global__ void k_gap(const float* __restrict__ x, float* __restrict__ g) {
    int bc = blockIdx.x;
    const float4* p4 = (const float4*)(x + (size_t)bc * HW_);
    float s = 0.f;
    for (int i = threadIdx.x; i < HW_/4; i += 256) {
        float4 v = p4[i];
        s += v.x + v.y + v.z + v.w;
    }
    for (int o = 32; o > 0; o >>= 1) s += __shfl_down(s, o, 64);
    __shared__ float ls[4];
    int wid = threadIdx.x >> 6, lane = threadIdx.x & 63;
    if (lane == 0) ls[wid] = s;
    __syncthreads();
    if (threadIdx.x == 0) g[bc] = (ls[0]+ls[1]+ls[2]+ls[3]) * (1.f/(float)HW_);
}

// --- routing MLP + softmax ---
__global__ void k_route(const float* __restrict__ g,
                        const float* r1w, const float* r1b,
                        const float* r2w, const float* r2b,
                        const float* r3w, const float* r3b,
                        float* __restrict__ rw) {
    int b = threadIdx.x;
    if (b >= B_) return;
    const float* gb = g + b * CIN_;
    float h[2];
    for (int j = 0; j < 2; ++j) {
        float s = r1b[j];
        for (int c = 0; c < CIN_; ++c) s += gb[c] * r1w[j*CIN_ + c];
        h[j] = fmaxf(s, 0.f);
    }
    float h2[4];
    for (int e = 0; e < 4; ++e)
        h2[e] = fmaxf(r2b[e] + h[0]*r2w[e*2] + h[1]*r2w[e*2+1], 0.f);
    float lg[4]; float m = -1e30f;
    for (int e = 0; e < 4; ++e) {
        float s = r3b[e];
        for (int j = 0; j < 4; ++j) s += h2[j]*r3w[e*4+j];
        lg[e] = s; m = fmaxf(m, s);
    }
    float den = 0.f;
    for (int e = 0; e < 4; ++e) { lg[e] = expf(lg[e]-m); den += lg[e]; }
    float inv = 1.f/den;
    for (int e = 0; e < 4; ++e) rw[b*4+e] = lg[e]*inv;
}

// --- x -> padded channels-last bf16: x_t[b][h+1][w+1][ci] ---
__global__ __launch_bounds__(256) void k_xt(const float* __restrict__ x,
                                            unsigned short* __restrict__ xt) {
    int h = blockIdx.x, b = blockIdx.y;
    int t = threadIdx.x;
    int w = t & 63, c8 = t >> 6;          // c8: 0..3
    unsigned short* orow = xt + (((size_t)b*66 + h + 1)*66 + (w + 1)) * 128;
    #pragma unroll
    for (int i = 0; i < 4; ++i) {
        int ci0 = i*32 + c8*8;
        short8v vv;
        #pragma unroll
        for (int j = 0; j < 8; ++j) {
            float f = x[(((size_t)b*CIN_ + ci0 + j)*H_ + h)*W_ + w];
            vv[j] = (short)f2bf(f);
        }
        *(short8v*)(orow + ci0) = vv;
    }
}

// --- combined expert weights -> bf16 [b][tap][co][ci] ---
__global__ __launch_bounds__(256) void k_wcomb(const float* __restrict__ ew,
                                               const float* __restrict__ rw,
                                               unsigned short* __restrict__ wc) {
    int co = blockIdx.x;
    int t = threadIdx.x;
    __shared__ float ewl[4*1152];
    __shared__ float rwl[64];
    #pragma unroll
    for (int e = 0; e < 4; ++e) {
        const float* src = ew + ((size_t)(e*COUT_ + co))*1152;
        for (int i = t; i < 1152; i += 256) ewl[e*1152 + i] = src[i];
    }
    if (t < 64) rwl[t] = rw[t];
    __syncthreads();
    for (int i = 0; i < 72; ++i) {
        int f = i*256 + t;
        int b = f / 1152;
        int rem = f - b*1152;
        int tap = rem >> 7, ci = rem & 127;
        int lidx = ci*9 + tap;
        float v = rwl[b*4+0]*ewl[0*1152+lidx] + rwl[b*4+1]*ewl[1*1152+lidx]
                + rwl[b*4+2]*ewl[2*1152+lidx] + rwl[b*4+3]*ewl[3*1152+lidx];
        wc[((size_t)(b*9 + tap)*COUT_ + co)*128 + ci] = f2bf(v);
    }
}

// --- MFMA implicit-GEMM conv: block = 64co x (4 rows x 64 cols) ---
__global__ __launch_bounds__(256) void k_conv(const unsigned short* __restrict__ xt,
                                              const unsigned short* __restrict__ wc,
                                              float* __restrict__ out) {
    __shared__ unsigned short xs[1600*8];   // 25.6 KB
    __shared__ unsigned short wl[2304*8];   // 36.9 KB
    int ht = blockIdx.x;
    int cb = blockIdx.y;
    int b  = blockIdx.z;
    int t  = threadIdx.x;
    int wv = t >> 6, lane = t & 63;
    int lr = lane & 15, kq = lane >> 4;
    int h0 = ht * 4;

    const unsigned short* xtb = xt + (size_t)b * 66*66*128;
    const unsigned short* wcb = wc + (size_t)b * 9*256*128;

    f32x4 acc[4][4];
    #pragma unroll
    for (int m = 0; m < 4; ++m)
        #pragma unroll
        for (int n = 0; n < 4; ++n) acc[m][n] = (f32x4){0.f,0.f,0.f,0.f};

    for (int ci0 = 0; ci0 < CIN_; ci0 += 32) {
        __syncthreads();
        for (int j = wv; j < 25; j += 4) {
            int s = j*64 + lane;
            if (s > 1583) s = 1583;
            int pos = s >> 2, q = s & 3;
            int rp = pos / 66, cp = pos - rp*66;
            const unsigned short* g = xtb + (((size_t)(h0 + rp)*66 + cp)*128 + ci0 + q*8);
            gl16(g, (const char*)xs + (size_t)j*1024);
        }
        for (int j = wv; j < 36; j += 4) {
            int s = j*64 + lane;
            int tap = s >> 8, col = (s >> 2) & 63, q = s & 3;
            const unsigned short* g = wcb + (((size_t)tap*COUT_ + cb*64 + col)*128 + ci0 + q*8);
            gl16(g, (const char*)wl + (size_t)j*1024);
        }
        asm volatile("s_waitcnt vmcnt(0)" ::: "memory");
        __syncthreads();

        #pragma unroll
        for (int dh = 0; dh < 3; ++dh) {
            #pragma unroll
            for (int dw = 0; dw < 3; ++dw) {
                int tap = dh*3 + dw;
                short8v af[4], bfv[4];
                #pragma unroll
                for (int m = 0; m < 4; ++m)
                    af[m] = *(const short8v*)(wl + ((size_t)tap*2048 + (m*16 + lr)*32 + kq*8));
                #pragma unroll
                for (int n = 0; n < 4; ++n)
                    bfv[n] = *(const short8v*)(xs + ((size_t)(wv+dh)*2112 + (n*16 + lr + dw)*32 + kq*8));
                #pragma unroll
                for (int m = 0; m < 4; ++m)
                    #pragma unroll
                    for (int n = 0; n < 4; ++n)
                        acc[m][n] = __builtin_amdgcn_mfma_f32_16x16x32_bf16(
                            af[m], bfv[n], acc[m][n], 0, 0, 0);
            }
        }
    }

    float* ob = out + ((size_t)b*COUT_ + cb*64)*HW_ + (h0 + wv)*W_;
    #pragma unroll
    for (int m = 0; m < 4; ++m)
        #pragma unroll
        for (int n = 0; n < 4; ++n) {
            f32x4 v = acc[m][n];
            #pragma unroll
            for (int r = 0; r < 4; ++r)
                ob[(size_t)(m*16 + kq*4 + r)*HW_ + n*16 + lr] = v[r];
        }
}

// --- SE channel attention ---
__global__ void k_ca(const float* __restrict__ p, const float* ca1w, const float* ca1b,
                     const float* ca2w, const float* ca2b, float* __restrict__ ca) {
    int b = blockIdx.x;
    __shared__ float h1[64];
    int t = threadIdx.x;   // 64
    const float* pb = p + b*COUT_;
    float s = ca1b[t];
    for (int c = 0; c < COUT_; ++c) s += pb[c] * ca1w[t*COUT_ + c];
    h1[t] = fmaxf(s, 0.f);
    __syncthreads();
    for (int i = 0; i < 4; ++i) {
        int co = t*4 + i;
        float s2 = ca2b[co];
        for (int j = 0; j < 64; ++j) s2 += h1[j] * ca2w[co*64 + j];
        ca[b*COUT_ + co] = 1.f/(1.f + expf(-s2));
    }
}

// --- SA weights -> bf16 [64 taps(padded)][256 c] ---
__global__ void k_wsa(const float* __restrict__ saw, unsigned short* __restrict__ wsa) {
    int i = blockIdx.x*256 + threadIdx.x;   // 16384 total, grid 64
    int tap = i >> 8, c = i & 255;
    float v = (tap < 49) ? saw[c*49 + tap] : 0.f;
    wsa[tap*256 + c] = f2bf(v);
}

// --- SA tap-contraction GEMM: u[b][tap][px] = sum_c wsa[tap][c]*mix[b][c][px] ---
// block: 64 px, 4 waves (wave = 16-tap m-frag); K=256 channels
__global__ __launch_bounds__(256) void k_sa_gemm(const float* __restrict__ mix,
                                                 const unsigned short* __restrict__ wsa,
                                                 float* __restrict__ u) {
    __shared__ unsigned short wl[16384];  // [64 tap][256 c] swizzled (32KB)
    __shared__ unsigned short bt[16384];  // [64 px][256 c] swizzled (32KB)
    int pxt = blockIdx.x;   // 0..63
    int b   = blockIdx.y;
    int t = threadIdx.x, wv = t >> 6, lane = t & 63;
    int lr = lane & 15, kq = lane >> 4;
    int px0 = pxt * 64;

    // stage wsa: 2048 16B slots, 32 slots per 512B row (FIXED decode)
    #pragma unroll
    for (int k = 0; k < 8; ++k) {
        int s = t + k*256;               // 0..2047
        int row = s >> 5, cs = s & 31;   // row 0..63, slot-in-row 0..31
        short8v v = *(const short8v*)(wsa + row*256 + cs*8);
        int off = row*512 + ((cs*16) ^ ((row & 7) << 4));
        *(short8v*)((char*)wl + off) = v;
    }
    // stage mix tile transposed to [px][c] bf16, swizzled.
    // wave wv owns channels [wv*64, wv*64+64); lane = px.
    {
        int px = lane;
        const float* mb = mix + ((size_t)b*COUT_)*HW_ + px0 + px;
        #pragma unroll
        for (int c8 = 0; c8 < 8; ++c8) {
            int cb = wv*64 + c8*8;
            short8v v;
            #pragma unroll
            for (int j = 0; j < 8; ++j)
                v[j] = (short)f2bf(mb[(size_t)(cb + j)*HW_]);
            int off = px*512 + ((cb*2) ^ ((px & 7) << 4));
            *(short8v*)((char*)bt + off) = v;
        }
    }
    __syncthreads();

    f32x4 acc[4];
    #pragma unroll
    for (int n = 0; n < 4; ++n) acc[n] = (f32x4){0.f,0.f,0.f,0.f};

    #pragma unroll
    for (int ks = 0; ks < 8; ++ks) {
        int ci0 = ks*32;
        int arow = wv*16 + lr;
        short8v a = *(const short8v*)((const char*)wl +
                        arow*512 + (((ci0 + kq*8)*2) ^ ((arow & 7) << 4)));
        #pragma unroll
        for (int n = 0; n < 4; ++n) {
            int prow = n*16 + lr;
            short8v bv = *(const short8v*)((const char*)bt +
                            prow*512 + (((ci0 + kq*8)*2) ^ ((prow & 7) << 4)));
            acc[n] = __builtin_amdgcn_mfma_f32_16x16x32_bf16(a, bv, acc[n], 0, 0, 0);
        }
    }

    float* ub = u + (size_t)b*64*HW_;
    #pragma unroll
    for (int n = 0; n < 4; ++n)
        #pragma unroll
        for (int r = 0; r < 4; ++r)
            ub[(size_t)(wv*16 + kq*4 + r)*HW_ + px0 + n*16 + lr] = acc[n][r];
}

// --- SA tap-shift reduce + sigmoid ---
__global__ void k_sared(const float* __restrict__ u, const float* __restrict__ sab,
                        float* __restrict__ sa) {
    int b = blockIdx.y;
    int h = blockIdx.x * 4 + (threadIdx.x >> 6);
    int w = threadIdx.x & 63;
    float s = sab[0];
    const float* ub = u + (size_t)b*64*HW_;
    #pragma unroll
    for (int dh = 0; dh < 7; ++dh) {
        int hh = h + dh - 3;
        if (hh < 0 || hh >= H_) continue;
        #pragma unroll
        for (int dw = 0; dw < 7; ++dw) {
            int ww = w + dw - 3;
            if (ww < 0 || ww >= W_) continue;
            s += ub[(size_t)(dh*7 + dw)*HW_ + hh*W_ + ww];
        }
    }
    sa[(size_t)b*HW_ + h*W_ + w] = 1.f/(1.f + expf(-s));
}

// --- out = mix*ca*sa (in place) + per-(b,c) partial sums for BN ---
__global__ void k_scale_stats(float* __restrict__ io, const float* __restrict__ ca,
                              const float* __restrict__ sa,
                              float* __restrict__ psum, float* __restrict__ psq) {
    int c = blockIdx.x & 255;
    int b = blockIdx.x >> 8;
    float cav = ca[b*COUT_ + c];
    float* pl = io + ((size_t)b*COUT_ + c) * HW_;
    const float* sab = sa + (size_t)b * HW_;
    float s = 0.f, sq = 0.f;
    for (int i = threadIdx.x; i < HW_/4; i += 256) {
        float4 v = ((float4*)pl)[i];
        float4 w = ((const float4*)sab)[i];
        v.x *= cav*w.x; v.y *= cav*w.y; v.z *= cav*w.z; v.w *= cav*w.w;
        ((float4*)pl)[i] = v;
        s  += v.x+v.y+v.z+v.w;
        sq += v.x*v.x+v.y*v.y+v.z*v.z+v.w*v.w;
    }
    for (int o = 32; o > 0; o >>= 1) { s += __shfl_down(s,o,64); sq += __shfl_down(sq,o,64); }
    __shared__ float ls[8];
    int wid = threadIdx.x>>6, lane = threadIdx.x&63;
    if (lane==0) { ls[wid]=s; ls[4+wid]=sq; }
    __syncthreads();
    if (threadIdx.x==0) {
        psum[b*COUT_+c] = ls[0]+ls[1]+ls[2]+ls[3];
        psq [b*COUT_+c] = ls[4]+ls[5]+ls[6]+ls[7];
    }
}

// --- finalize BN scale/shift ---
__global__ void k_bnfin(const float* __restrict__ psum, const float* __restrict__ psq,
                        const float* __restrict__ gamma, const float* __restrict__ beta,
                        float* __restrict__ scale, float* __restrict__ shift) {
    int c = threadIdx.x; // 256
    float s=0.f, q=0.f;
    for (int b = 0; b < B_; ++b) { s += psum[b*COUT_+c]; q += psq[b*COUT_+c]; }
    float n = (float)(B_*HW_);
    float mean = s/n;
    float var = q/n - mean*mean;
    float sc = gamma[c] * rsqrtf(var + 1e-5f);
    scale[c] = sc;
    shift[c] = beta[c] - mean*sc;
}

// --- BN + ReLU in place ---
__global__ void k_bnapply(float* __restrict__ io, const float* __restrict__ scale,
                          const float* __restrict__ shift) {
    size_t i = (size_t)blockIdx.x * 256 + threadIdx.x;
    int c = (int)((i >> 10) & 255);
    float4 v = ((float4*)io)[i];
    float sc = scale[c], sh = shift[c];
    v.x = fmaxf(fmaf(v.x,sc,sh), 0.f); v.y = fmaxf(fmaf(v.y,sc,sh), 0.f);
    v.z = fmaxf(fmaf(v.z,sc,sh), 0.f); v.w = fmaxf(fmaf(v.w,sc,sh), 0.f);
    ((float4*)io)[i] = v;
}

extern "C" void kernel_launch(void* const* d_in, const int* in_sizes, int n_in,
                              void* d_out, int out_size, void* d_ws, size_t ws_size,
                              hipStream_t stream) {
    const float* x    = (const float*)d_in[0];
    const float* ew   = (const float*)d_in[1];
    const float* r1w  = (const float*)d_in[2];
    const float* r1b  = (const float*)d_in[3];
    const float* r2w  = (const float*)d_in[4];
    const float* r2b  = (const float*)d_in[5];
    const float* r3w  = (const float*)d_in[6];
    const float* r3b  = (const float*)d_in[7];
    const float* ca1w = (const float*)d_in[8];
    const float* ca1b = (const float*)d_in[9];
    const float* ca2w = (const float*)d_in[10];
    const float* ca2b = (const float*)d_in[11];
    const float* saw  = (const float*)d_in[12];
    const float* sab  = (const float*)d_in[13];
    const float* gm   = (const float*)d_in[14];
    const float* bt   = (const float*)d_in[15];
    float* out = (float*)d_out;
    float* ws  = (float*)d_ws;
    unsigned short* wcb = (unsigned short*)(ws + WS_WCB_F);
    unsigned short* xt  = (unsigned short*)(ws + WS_XT_F);
    unsigned short* wsa = (unsigned short*)(ws + WS_WSA);
    float* u = ws + WS_U_F;   // overlaps xt region (xt dead after k_conv)

    hipMemsetAsync((void*)xt, 0, XT_BYTES, stream);
    k_xt<<<dim3(64,16), 256, 0, stream>>>(x, xt);
    k_gap<<<B_*CIN_, 256, 0, stream>>>(x, ws+WS_G);
    k_route<<<1, 64, 0, stream>>>(ws+WS_G, r1w, r1b, r2w, r2b, r3w, r3b, ws+WS_RW);
    k_wcomb<<<COUT_, 256, 0, stream>>>(ew, ws+WS_RW, wcb);
    k_wsa<<<64, 256, 0, stream>>>(saw, wsa);
    k_conv<<<dim3(16,4,16), 256, 0, stream>>>(xt, wcb, out);
    k_gap<<<B_*COUT_, 256, 0, stream>>>(out, ws+WS_P);
    k_ca<<<B_, 64, 0, stream>>>(ws+WS_P, ca1w, ca1b, ca2w, ca2b, ws+WS_CA);
    k_sa_gemm<<<dim3(64,16), 256, 0, stream>>>(out, wsa, u);
    k_sared<<<dim3(16,16), 256, 0, stream>>>(u, sab, ws+WS_SA);
    k_scale_stats<<<B_*COUT_, 256, 0, stream>>>(out, ws+WS_CA, ws+WS_SA, ws+WS_PSUM, ws+WS_PSQ);
    k_bnfin<<<1, 256, 0, stream>>>(ws+WS_PSUM, ws+WS_PSQ, gm, bt, ws+WS_BNSCALE, ws+WS_BNSHIFT);
    k_bnapply<<<16384, 256, 0, stream>>>(out, ws+WS_BNSCALE, ws+WS_BNSHIFT);
}

// Round 5
// 165.897 us; speedup vs baseline: 6.0960x; 1.1738x over previous
//
#include <hip/hip_runtime.h>
#include <math.h>

#define B_    16
#define CIN_  128
#define COUT_ 256
#define H_    64
#define W_    64
#define HW_   4096

typedef __attribute__((ext_vector_type(8))) short short8v;
typedef __attribute__((ext_vector_type(4))) float f32x4;

// workspace layout (float offsets)
#define WS_GPX     0          // [16][64][128] x-gap partials = 131072
#define WS_RW      131072     // 64
#define WS_CP      131136     // conv gap partials [16][16][256] = 65536
#define WS_CA      196672     // 4096
#define WS_PSUM    200768     // 4096
#define WS_PSQ     204864     // 4096
#define WS_BNSCALE 208960     // 256
#define WS_BNSHIFT 209216     // 256
#define WS_SA      209472     // 65536
#define WS_WSA     275008     // 16384 bf16 = 8192 floats
#define WS_WCB_F   283200     // bf16 [16][9][256][128] = 4718592 bf16
#define WS_XT_F    2642496    // bf16 [16][66][66][128] = 8921088 bf16
#define WS_U_F     WS_XT_F    // fp32 [16][64][4096] (xt dead after conv)

static __device__ __forceinline__ unsigned short f2bf(float f) {
    union { float f; unsigned int u; } v; v.f = f;
    unsigned int u = v.u;
    return (unsigned short)((u + 0x7FFFu + ((u >> 16) & 1u)) >> 16);  // RTNE
}

__device__ __forceinline__ void gl16(const void* g, const void* l) {
    __builtin_amdgcn_global_load_lds(
        (const __attribute__((address_space(1))) unsigned int*)g,
        (__attribute__((address_space(3))) unsigned int*)l, 16, 0, 0);
}

// --- x -> padded channels-last bf16 + fused x-GAP partials + halo zeroing ---
__global__ __launch_bounds__(256) void k_xt(const float* __restrict__ x,
                                            unsigned short* __restrict__ xt,
                                            float* __restrict__ gpart) {
    int h = blockIdx.x, b = blockIdx.y;
    int t = threadIdx.x;
    int w = t & 63, c8 = t >> 6;
    unsigned short* xtb = xt + (size_t)b * 66*66*128;
    unsigned short* orow = xtb + (((size_t)(h+1))*66 + (w+1))*128;
    float* gp = gpart + ((size_t)b*64 + h)*128;
    #pragma unroll
    for (int i = 0; i < 4; ++i) {
        int ci0 = i*32 + c8*8;
        float f[8];
        short8v vv;
        #pragma unroll
        for (int j = 0; j < 8; ++j) {
            f[j] = x[(((size_t)b*CIN_ + ci0 + j)*H_ + h)*W_ + w];
            vv[j] = (short)f2bf(f[j]);
        }
        *(short8v*)(orow + ci0) = vv;
        #pragma unroll
        for (int j = 0; j < 8; ++j) {
            float s = f[j];
            s += __shfl_down(s, 32, 64);
            s += __shfl_down(s, 16, 64);
            s += __shfl_down(s, 8, 64);
            s += __shfl_down(s, 4, 64);
            s += __shfl_down(s, 2, 64);
            s += __shfl_down(s, 1, 64);
            f[j] = s;
        }
        if (w == 0) {
            #pragma unroll
            for (int j = 0; j < 8; ++j) gp[ci0 + j] = f[j];
        }
    }
    // halo: cols 0 and 65 of this row
    xtb[(((size_t)(h+1))*66 + (t >> 7)*65)*128 + (t & 127)] = 0;
    // halo: rows 0 and 65
    if (h == 0 || h == 63) {
        int r = (h == 0) ? 0 : 65;
        unsigned short* rowp = xtb + ((size_t)r*66)*128;   // 8448 shorts
        for (int i = t; i < 1056; i += 256)
            *(short8v*)(rowp + (size_t)i*8) = (short8v){0,0,0,0,0,0,0,0};
    }
}

// --- routing: reduce x-gap partials + MLP + softmax (grid = B) ---
__global__ void k_route(const float* __restrict__ gpart,
                        const float* r1w, const float* r1b,
                        const float* r2w, const float* r2b,
                        const float* r3w, const float* r3b,
                        float* __restrict__ rw) {
    int b = blockIdx.x;
    int t = threadIdx.x;  // 128
    __shared__ float gl_[128];
    float s = 0.f;
    for (int h = 0; h < 64; ++h) s += gpart[((size_t)b*64 + h)*128 + t];
    gl_[t] = s * (1.f/4096.f);
    __syncthreads();
    if (t == 0) {
        float h1[2];
        for (int j = 0; j < 2; ++j) {
            float acc = r1b[j];
            for (int c = 0; c < CIN_; ++c) acc += gl_[c]*r1w[j*CIN_+c];
            h1[j] = fmaxf(acc, 0.f);
        }
        float h2[4];
        for (int e = 0; e < 4; ++e)
            h2[e] = fmaxf(r2b[e] + h1[0]*r2w[e*2] + h1[1]*r2w[e*2+1], 0.f);
        float lg[4], m = -1e30f;
        for (int e = 0; e < 4; ++e) {
            float acc = r3b[e];
            for (int j = 0; j < 4; ++j) acc += h2[j]*r3w[e*4+j];
            lg[e] = acc; m = fmaxf(m, acc);
        }
        float den = 0.f;
        for (int e = 0; e < 4; ++e) { lg[e] = expf(lg[e]-m); den += lg[e]; }
        float inv = 1.f/den;
        for (int e = 0; e < 4; ++e) rw[b*4+e] = lg[e]*inv;
    }
}

// --- combined expert weights -> bf16 [b][tap][co][ci]; blocks >=256 do wsa ---
__global__ __launch_bounds__(256) void k_wcomb(const float* __restrict__ ew,
                                               const float* __restrict__ rw,
                                               unsigned short* __restrict__ wc,
                                               const float* __restrict__ saw,
                                               unsigned short* __restrict__ wsa) {
    int t = threadIdx.x;
    if (blockIdx.x >= COUT_) {
        int i = (blockIdx.x - COUT_)*256 + t;   // 0..16383
        int tap = i >> 8, c = i & 255;
        float v = (tap < 49) ? saw[c*49 + tap] : 0.f;
        wsa[tap*256 + c] = f2bf(v);
        return;
    }
    int co = blockIdx.x;
    __shared__ float ewl[4*1152];
    __shared__ float rwl[64];
    #pragma unroll
    for (int e = 0; e < 4; ++e) {
        const float* src = ew + ((size_t)(e*COUT_ + co))*1152;
        for (int i = t; i < 1152; i += 256) ewl[e*1152 + i] = src[i];
    }
    if (t < 64) rwl[t] = rw[t];
    __syncthreads();
    for (int i = 0; i < 72; ++i) {
        int f = i*256 + t;
        int b = f / 1152;
        int rem = f - b*1152;
        int tap = rem >> 7, ci = rem & 127;
        int lidx = ci*9 + tap;
        float v = rwl[b*4+0]*ewl[0*1152+lidx] + rwl[b*4+1]*ewl[1*1152+lidx]
                + rwl[b*4+2]*ewl[2*1152+lidx] + rwl[b*4+3]*ewl[3*1152+lidx];
        wc[((size_t)(b*9 + tap)*COUT_ + co)*128 + ci] = f2bf(v);
    }
}

// --- MFMA implicit-GEMM conv + fused mix-GAP partials ---
// LDS: paired-row XOR swizzle (c_phys = c_log ^ (P&7), P = 128B row-pair)
// staged via pre-swizzled global source, gl16 dest linear.
__global__ __launch_bounds__(256) void k_conv(const unsigned short* __restrict__ xt,
                                              const unsigned short* __restrict__ wc,
                                              float* __restrict__ out,
                                              float* __restrict__ cpart) {
    __shared__ unsigned short xs[1600*8];   // 25.6 KB
    __shared__ unsigned short wl[2304*8];   // 36.9 KB
    __shared__ float gsl[4][64];
    int ht = blockIdx.x;
    int cb = blockIdx.y;
    int b  = blockIdx.z;
    int t  = threadIdx.x;
    int wv = t >> 6, lane = t & 63;
    int lr = lane & 15, kq = lane >> 4;
    int h0 = ht * 4;

    const unsigned short* xtb = xt + (size_t)b * 66*66*128;
    const unsigned short* wcb = wc + (size_t)b * 9*256*128;

    // thread-constant swizzled byte offset for weight frags
    int wboff = (lr >> 1)*128 + ((((lr & 1) << 2) + kq) ^ (lr >> 1))*16;

    f32x4 acc[4][4];
    #pragma unroll
    for (int m = 0; m < 4; ++m)
        #pragma unroll
        for (int n = 0; n < 4; ++n) acc[m][n] = (f32x4){0.f,0.f,0.f,0.f};

    for (int ci0 = 0; ci0 < CIN_; ci0 += 32) {
        __syncthreads();
        // stage x tile (1584 slots + clamp pad): slot -> swizzled global source
        for (int j = wv; j < 25; j += 4) {
            int s = j*64 + lane;
            if (s > 1583) s = 1583;
            int P = s >> 3, cph = s & 7;
            int clg = cph ^ (P & 7);
            int pos = P*2 + (clg >> 2), kq2 = clg & 3;
            int rp = pos / 66, cp = pos - rp*66;
            const unsigned short* g = xtb + (((size_t)(h0+rp)*66 + cp)*128 + ci0 + kq2*8);
            gl16(g, (const char*)xs + (size_t)j*1024);
        }
        // stage weights (2304 slots)
        for (int j = wv; j < 36; j += 4) {
            int s = j*64 + lane;
            int P = s >> 3, cph = s & 7;
            int clg = cph ^ (P & 7);
            int R = P*2 + (clg >> 2);          // tap*64 + col
            int tap = R >> 6, col = R & 63, kq2 = clg & 3;
            const unsigned short* g = wcb + (((size_t)tap*COUT_ + cb*64 + col)*128 + ci0 + kq2*8);
            gl16(g, (const char*)wl + (size_t)j*1024);
        }
        asm volatile("s_waitcnt vmcnt(0)" ::: "memory");
        __syncthreads();

        #pragma unroll
        for (int dh = 0; dh < 3; ++dh) {
            #pragma unroll
            for (int dw = 0; dw < 3; ++dw) {
                int tap = dh*3 + dw;
                int pos0 = (wv + dh)*66 + lr + dw;
                int p2 = pos0 >> 1;
                int xboff = p2*128 + ((((pos0 & 1) << 2) + kq) ^ (p2 & 7))*16;
                short8v af[4], bfv[4];
                #pragma unroll
                for (int m = 0; m < 4; ++m)
                    af[m] = *(const short8v*)((const char*)wl + tap*4096 + m*1024 + wboff);
                #pragma unroll
                for (int n = 0; n < 4; ++n)
                    bfv[n] = *(const short8v*)((const char*)xs + xboff + n*1024);
                #pragma unroll
                for (int m = 0; m < 4; ++m)
                    #pragma unroll
                    for (int n = 0; n < 4; ++n)
                        acc[m][n] = __builtin_amdgcn_mfma_f32_16x16x32_bf16(
                            af[m], bfv[n], acc[m][n], 0, 0, 0);
            }
        }
    }

    // C write
    float* ob = out + ((size_t)b*COUT_ + cb*64)*HW_ + (h0 + wv)*W_;
    #pragma unroll
    for (int m = 0; m < 4; ++m)
        #pragma unroll
        for (int n = 0; n < 4; ++n) {
            f32x4 v = acc[m][n];
            #pragma unroll
            for (int r = 0; r < 4; ++r)
                ob[(size_t)(m*16 + kq*4 + r)*HW_ + n*16 + lr] = v[r];
        }

    // fused GAP partials: sum over this block's 256 px per co
    float gp[4][4];
    #pragma unroll
    for (int m = 0; m < 4; ++m)
        #pragma unroll
        for (int r = 0; r < 4; ++r)
            gp[m][r] = acc[m][0][r] + acc[m][1][r] + acc[m][2][r] + acc[m][3][r];
    #pragma unroll
    for (int o = 8; o > 0; o >>= 1)
        #pragma unroll
        for (int m = 0; m < 4; ++m)
            #pragma unroll
            for (int r = 0; r < 4; ++r)
                gp[m][r] += __shfl_down(gp[m][r], o, 64);
    if ((lane & 15) == 0) {
        #pragma unroll
        for (int m = 0; m < 4; ++m)
            #pragma unroll
            for (int r = 0; r < 4; ++r)
                gsl[wv][m*16 + kq*4 + r] = gp[m][r];
    }
    __syncthreads();
    if (t < 64) {
        float s = gsl[0][t] + gsl[1][t] + gsl[2][t] + gsl[3][t];
        cpart[((size_t)b*16 + ht)*COUT_ + cb*64 + t] = s;
    }
}

// --- SE channel attention (reduces conv gap partials first) ---
__global__ void k_ca(const float* __restrict__ cpart, const float* ca1w, const float* ca1b,
                     const float* ca2w, const float* ca2b, float* __restrict__ ca) {
    int b = blockIdx.x;
    int t = threadIdx.x;   // 64
    __shared__ float pfull[256];
    __shared__ float h1[64];
    for (int i = t; i < 256; i += 64) {
        float s = 0.f;
        for (int h = 0; h < 16; ++h) s += cpart[((size_t)b*16 + h)*COUT_ + i];
        pfull[i] = s * (1.f/(float)HW_);
    }
    __syncthreads();
    float s = ca1b[t];
    for (int c = 0; c < COUT_; ++c) s += pfull[c] * ca1w[t*COUT_ + c];
    h1[t] = fmaxf(s, 0.f);
    __syncthreads();
    for (int i = 0; i < 4; ++i) {
        int co = t*4 + i;
        float s2 = ca2b[co];
        for (int j = 0; j < 64; ++j) s2 += h1[j] * ca2w[co*64 + j];
        ca[b*COUT_ + co] = 1.f/(1.f + expf(-s2));
    }
}

// --- SA tap-contraction GEMM: u[b][tap][px] = sum_c wsa[tap][c]*mix[b][c][px] ---
__global__ __launch_bounds__(256) void k_sa_gemm(const float* __restrict__ mix,
                                                 const unsigned short* __restrict__ wsa,
                                                 float* __restrict__ u) {
    __shared__ unsigned short wl[16384];  // [64 tap][256 c] swizzled (32KB)
    __shared__ unsigned short bt[16384];  // [64 px][256 c] swizzled (32KB)
    int pxt = blockIdx.x;   // 0..63
    int b   = blockIdx.y;
    int t = threadIdx.x, wv = t >> 6, lane = t & 63;
    int lr = lane & 15, kq = lane >> 4;
    int px0 = pxt * 64;

    #pragma unroll
    for (int k = 0; k < 8; ++k) {
        int s = t + k*256;               // 0..2047
        int row = s >> 5, cs = s & 31;
        short8v v = *(const short8v*)(wsa + row*256 + cs*8);
        int off = row*512 + ((cs*16) ^ ((row & 7) << 4));
        *(short8v*)((char*)wl + off) = v;
    }
    {
        int px = lane;
        const float* mb = mix + ((size_t)b*COUT_)*HW_ + px0 + px;
        #pragma unroll
        for (int c8 = 0; c8 < 8; ++c8) {
            int cb = wv*64 + c8*8;
            short8v v;
            #pragma unroll
            for (int j = 0; j < 8; ++j)
                v[j] = (short)f2bf(mb[(size_t)(cb + j)*HW_]);
            int off = px*512 + ((cb*2) ^ ((px & 7) << 4));
            *(short8v*)((char*)bt + off) = v;
        }
    }
    __syncthreads();

    f32x4 acc[4];
    #pragma unroll
    for (int n = 0; n < 4; ++n) acc[n] = (f32x4){0.f,0.f,0.f,0.f};

    #pragma unroll
    for (int ks = 0; ks < 8; ++ks) {
        int ci0 = ks*32;
        int arow = wv*16 + lr;
        short8v a = *(const short8v*)((const char*)wl +
                        arow*512 + (((ci0 + kq*8)*2) ^ ((arow & 7) << 4)));
        #pragma unroll
        for (int n = 0; n < 4; ++n) {
            int prow = n*16 + lr;
            short8v bv = *(const short8v*)((const char*)bt +
                            prow*512 + (((ci0 + kq*8)*2) ^ ((prow & 7) << 4)));
            acc[n] = __builtin_amdgcn_mfma_f32_16x16x32_bf16(a, bv, acc[n], 0, 0, 0);
        }
    }

    float* ub = u + (size_t)b*64*HW_;
    #pragma unroll
    for (int n = 0; n < 4; ++n)
        #pragma unroll
        for (int r = 0; r < 4; ++r)
            ub[(size_t)(wv*16 + kq*4 + r)*HW_ + px0 + n*16 + lr] = acc[n][r];
}

// --- SA tap-shift reduce + sigmoid ---
__global__ void k_sared(const float* __restrict__ u, const float* __restrict__ sab,
                        float* __restrict__ sa) {
    int b = blockIdx.y;
    int h = blockIdx.x * 4 + (threadIdx.x >> 6);
    int w = threadIdx.x & 63;
    float s = sab[0];
    const float* ub = u + (size_t)b*64*HW_;
    #pragma unroll
    for (int dh = 0; dh < 7; ++dh) {
        int hh = h + dh - 3;
        if (hh < 0 || hh >= H_) continue;
        #pragma unroll
        for (int dw = 0; dw < 7; ++dw) {
            int ww = w + dw - 3;
            if (ww < 0 || ww >= W_) continue;
            s += ub[(size_t)(dh*7 + dw)*HW_ + hh*W_ + ww];
        }
    }
    sa[(size_t)b*HW_ + h*W_ + w] = 1.f/(1.f + expf(-s));
}

// --- BN stats over mix*ca*sa (read-only) ---
__global__ void k_stats(const float* __restrict__ io, const float* __restrict__ ca,
                        const float* __restrict__ sa,
                        float* __restrict__ psum, float* __restrict__ psq) {
    int c = blockIdx.x & 255;
    int b = blockIdx.x >> 8;
    float cav = ca[b*COUT_ + c];
    const float* pl = io + ((size_t)b*COUT_ + c) * HW_;
    const float* sab = sa + (size_t)b * HW_;
    float s = 0.f, sq = 0.f;
    for (int i = threadIdx.x; i < HW_/4; i += 256) {
        float4 v = ((const float4*)pl)[i];
        float4 w = ((const float4*)sab)[i];
        v.x *= cav*w.x; v.y *= cav*w.y; v.z *= cav*w.z; v.w *= cav*w.w;
        s  += v.x+v.y+v.z+v.w;
        sq += v.x*v.x+v.y*v.y+v.z*v.z+v.w*v.w;
    }
    for (int o = 32; o > 0; o >>= 1) { s += __shfl_down(s,o,64); sq += __shfl_down(sq,o,64); }
    __shared__ float ls[8];
    int wid = threadIdx.x>>6, lane = threadIdx.x&63;
    if (lane==0) { ls[wid]=s; ls[4+wid]=sq; }
    __syncthreads();
    if (threadIdx.x==0) {
        psum[b*COUT_+c] = ls[0]+ls[1]+ls[2]+ls[3];
        psq [b*COUT_+c] = ls[4]+ls[5]+ls[6]+ls[7];
    }
}

// --- finalize BN scale/shift ---
__global__ void k_bnfin(const float* __restrict__ psum, const float* __restrict__ psq,
                        const float* __restrict__ gamma, const float* __restrict__ beta,
                        float* __restrict__ scale, float* __restrict__ shift) {
    int c = threadIdx.x; // 256
    float s=0.f, q=0.f;
    for (int b = 0; b < B_; ++b) { s += psum[b*COUT_+c]; q += psq[b*COUT_+c]; }
    float n = (float)(B_*HW_);
    float mean = s/n;
    float var = q/n - mean*mean;
    float sc = gamma[c] * rsqrtf(var + 1e-5f);
    scale[c] = sc;
    shift[c] = beta[c] - mean*sc;
}

// --- recompute mix*ca*sa, BN + ReLU, in place ---
__global__ void k_bnapply(float* __restrict__ io, const float* __restrict__ ca,
                          const float* __restrict__ sa,
                          const float* __restrict__ scale, const float* __restrict__ shift) {
    size_t i = (size_t)blockIdx.x * 256 + threadIdx.x;   // float4 idx
    int c = (int)((i >> 10) & 255);
    int b = (int)(i >> 18);
    int px4 = (int)(i & 1023);
    float cav = ca[b*COUT_ + c];
    float sc = scale[c], sh = shift[c];
    float4 v = ((float4*)io)[i];
    float4 w = ((const float4*)(sa + (size_t)b*HW_))[px4];
    v.x = fmaxf(fmaf(v.x*cav*w.x, sc, sh), 0.f);
    v.y = fmaxf(fmaf(v.y*cav*w.y, sc, sh), 0.f);
    v.z = fmaxf(fmaf(v.z*cav*w.z, sc, sh), 0.f);
    v.w = fmaxf(fmaf(v.w*cav*w.w, sc, sh), 0.f);
    ((float4*)io)[i] = v;
}

extern "C" void kernel_launch(void* const* d_in, const int* in_sizes, int n_in,
                              void* d_out, int out_size, void* d_ws, size_t ws_size,
                              hipStream_t stream) {
    const float* x    = (const float*)d_in[0];
    const float* ew   = (const float*)d_in[1];
    const float* r1w  = (const float*)d_in[2];
    const float* r1b  = (const float*)d_in[3];
    const float* r2w  = (const float*)d_in[4];
    const float* r2b  = (const float*)d_in[5];
    const float* r3w  = (const float*)d_in[6];
    const float* r3b  = (const float*)d_in[7];
    const float* ca1w = (const float*)d_in[8];
    const float* ca1b = (const float*)d_in[9];
    const float* ca2w = (const float*)d_in[10];
    const float* ca2b = (const float*)d_in[11];
    const float* saw  = (const float*)d_in[12];
    const float* sab  = (const float*)d_in[13];
    const float* gm   = (const float*)d_in[14];
    const float* bt   = (const float*)d_in[15];
    float* out = (float*)d_out;
    float* ws  = (float*)d_ws;
    unsigned short* wcb = (unsigned short*)(ws + WS_WCB_F);
    unsigned short* xt  = (unsigned short*)(ws + WS_XT_F);
    unsigned short* wsa = (unsigned short*)(ws + WS_WSA);
    float* u = ws + WS_U_F;   // overlaps xt region (xt dead after k_conv)

    k_xt<<<dim3(64,16), 256, 0, stream>>>(x, xt, ws+WS_GPX);
    k_route<<<16, 128, 0, stream>>>(ws+WS_GPX, r1w, r1b, r2w, r2b, r3w, r3b, ws+WS_RW);
    k_wcomb<<<320, 256, 0, stream>>>(ew, ws+WS_RW, wcb, saw, wsa);
    k_conv<<<dim3(16,4,16), 256, 0, stream>>>(xt, wcb, out, ws+WS_CP);
    k_ca<<<B_, 64, 0, stream>>>(ws+WS_CP, ca1w, ca1b, ca2w, ca2b, ws+WS_CA);
    k_sa_gemm<<<dim3(64,16), 256, 0, stream>>>(out, wsa, u);
    k_sared<<<dim3(16,16), 256, 0, stream>>>(u, sab, ws+WS_SA);
    k_stats<<<B_*COUT_, 256, 0, stream>>>(out, ws+WS_CA, ws+WS_SA, ws+WS_PSUM, ws+WS_PSQ);
    k_bnfin<<<1, 256, 0, stream>>>(ws+WS_PSUM, ws+WS_PSQ, gm, bt, ws+WS_BNSCALE, ws+WS_BNSHIFT);
    k_bnapply<<<16384, 256, 0, stream>>>(out, ws+WS_CA, ws+WS_SA, ws+WS_BNSCALE, ws+WS_BNSHIFT);
}

// Round 6
// 152.298 us; speedup vs baseline: 6.6403x; 1.0893x over previous
//
#include <hip/hip_runtime.h>
#include <math.h>

#define B_    16
#define CIN_  128
#define COUT_ 256
#define H_    64
#define W_    64
#define HW_   4096

typedef __attribute__((ext_vector_type(8))) short short8v;
typedef __attribute__((ext_vector_type(4))) float f32x4;

// workspace layout (float offsets)
#define WS_GPX     0          // [16][64][128] x-gap partials = 131072
#define WS_RW      131072     // 64
#define WS_CP      131136     // conv gap partials [16][16][256] = 65536
#define WS_CA      196672     // 4096
#define WS_PSUM    200768     // 4096
#define WS_PSQ     204864     // 4096
#define WS_BNSCALE 208960     // 256
#define WS_BNSHIFT 209216     // 256
#define WS_SA      209472     // 65536
#define WS_WSA     275008     // 16384 bf16 = 8192 floats
#define WS_WCB_F   283200     // bf16 [16][9][256][128] = 4718592 bf16 = 2359296 floats
#define WS_XT_F    2642496    // bf16 [16][66][66][128] = 8921088 bf16 = 4460544 floats
#define WS_U_F     WS_XT_F    // fp32 [16][64][4096] = 4194304 floats (xt dead after conv)
#define WS_MIX_F   7103040    // bf16 [16][256][4096] = 16777216 bf16 = 8388608 floats

static __device__ __forceinline__ unsigned short f2bf(float f) {
    union { float f; unsigned int u; } v; v.f = f;
    unsigned int u = v.u;
    return (unsigned short)((u + 0x7FFFu + ((u >> 16) & 1u)) >> 16);  // RTNE
}
static __device__ __forceinline__ float bf2f(unsigned short h) {
    union { unsigned int u; float f; } v; v.u = ((unsigned int)h) << 16;
    return v.f;
}

__device__ __forceinline__ void gl16(const void* g, const void* l) {
    __builtin_amdgcn_global_load_lds(
        (const __attribute__((address_space(1))) unsigned int*)g,
        (__attribute__((address_space(3))) unsigned int*)l, 16, 0, 0);
}

// --- x -> padded channels-last bf16 + fused x-GAP partials + halo zeroing ---
__global__ __launch_bounds__(256) void k_xt(const float* __restrict__ x,
                                            unsigned short* __restrict__ xt,
                                            float* __restrict__ gpart) {
    int h = blockIdx.x, b = blockIdx.y;
    int t = threadIdx.x;
    int w = t & 63, c8 = t >> 6;
    unsigned short* xtb = xt + (size_t)b * 66*66*128;
    unsigned short* orow = xtb + (((size_t)(h+1))*66 + (w+1))*128;
    float* gp = gpart + ((size_t)b*64 + h)*128;
    #pragma unroll
    for (int i = 0; i < 4; ++i) {
        int ci0 = i*32 + c8*8;
        float f[8];
        short8v vv;
        #pragma unroll
        for (int j = 0; j < 8; ++j) {
            f[j] = x[(((size_t)b*CIN_ + ci0 + j)*H_ + h)*W_ + w];
            vv[j] = (short)f2bf(f[j]);
        }
        *(short8v*)(orow + ci0) = vv;
        #pragma unroll
        for (int j = 0; j < 8; ++j) {
            float s = f[j];
            s += __shfl_down(s, 32, 64);
            s += __shfl_down(s, 16, 64);
            s += __shfl_down(s, 8, 64);
            s += __shfl_down(s, 4, 64);
            s += __shfl_down(s, 2, 64);
            s += __shfl_down(s, 1, 64);
            f[j] = s;
        }
        if (w == 0) {
            #pragma unroll
            for (int j = 0; j < 8; ++j) gp[ci0 + j] = f[j];
        }
    }
    // halo: cols 0 and 65 of this row
    xtb[(((size_t)(h+1))*66 + (t >> 7)*65)*128 + (t & 127)] = 0;
    // halo: rows 0 and 65
    if (h == 0 || h == 63) {
        int r = (h == 0) ? 0 : 65;
        unsigned short* rowp = xtb + ((size_t)r*66)*128;   // 8448 shorts
        for (int i = t; i < 1056; i += 256)
            *(short8v*)(rowp + (size_t)i*8) = (short8v){0,0,0,0,0,0,0,0};
    }
}

// --- routing: reduce x-gap partials + MLP + softmax (grid = B) ---
__global__ void k_route(const float* __restrict__ gpart,
                        const float* r1w, const float* r1b,
                        const float* r2w, const float* r2b,
                        const float* r3w, const float* r3b,
                        float* __restrict__ rw) {
    int b = blockIdx.x;
    int t = threadIdx.x;  // 128
    __shared__ float gl_[128];
    float s = 0.f;
    for (int h = 0; h < 64; ++h) s += gpart[((size_t)b*64 + h)*128 + t];
    gl_[t] = s * (1.f/4096.f);
    __syncthreads();
    if (t == 0) {
        float h1[2];
        for (int j = 0; j < 2; ++j) {
            float acc = r1b[j];
            for (int c = 0; c < CIN_; ++c) acc += gl_[c]*r1w[j*CIN_+c];
            h1[j] = fmaxf(acc, 0.f);
        }
        float h2[4];
        for (int e = 0; e < 4; ++e)
            h2[e] = fmaxf(r2b[e] + h1[0]*r2w[e*2] + h1[1]*r2w[e*2+1], 0.f);
        float lg[4], m = -1e30f;
        for (int e = 0; e < 4; ++e) {
            float acc = r3b[e];
            for (int j = 0; j < 4; ++j) acc += h2[j]*r3w[e*4+j];
            lg[e] = acc; m = fmaxf(m, acc);
        }
        float den = 0.f;
        for (int e = 0; e < 4; ++e) { lg[e] = expf(lg[e]-m); den += lg[e]; }
        float inv = 1.f/den;
        for (int e = 0; e < 4; ++e) rw[b*4+e] = lg[e]*inv;
    }
}

// --- combined expert weights -> bf16 [b][tap][co][ci]; blocks >=256 do wsa ---
__global__ __launch_bounds__(256) void k_wcomb(const float* __restrict__ ew,
                                               const float* __restrict__ rw,
                                               unsigned short* __restrict__ wc,
                                               const float* __restrict__ saw,
                                               unsigned short* __restrict__ wsa) {
    int t = threadIdx.x;
    if (blockIdx.x >= COUT_) {
        int i = (blockIdx.x - COUT_)*256 + t;   // 0..16383
        int tap = i >> 8, c = i & 255;
        float v = (tap < 49) ? saw[c*49 + tap] : 0.f;
        wsa[tap*256 + c] = f2bf(v);
        return;
    }
    int co = blockIdx.x;
    __shared__ float ewl[4*1152];
    __shared__ float rwl[64];
    #pragma unroll
    for (int e = 0; e < 4; ++e) {
        const float* src = ew + ((size_t)(e*COUT_ + co))*1152;
        for (int i = t; i < 1152; i += 256) ewl[e*1152 + i] = src[i];
    }
    if (t < 64) rwl[t] = rw[t];
    __syncthreads();
    for (int i = 0; i < 72; ++i) {
        int f = i*256 + t;
        int b = f / 1152;
        int rem = f - b*1152;
        int tap = rem >> 7, ci = rem & 127;
        int lidx = ci*9 + tap;
        float v = rwl[b*4+0]*ewl[0*1152+lidx] + rwl[b*4+1]*ewl[1*1152+lidx]
                + rwl[b*4+2]*ewl[2*1152+lidx] + rwl[b*4+3]*ewl[3*1152+lidx];
        wc[((size_t)(b*9 + tap)*COUT_ + co)*128 + ci] = f2bf(v);
    }
}

// --- MFMA implicit-GEMM conv (round-4 linear LDS addressing) + fused mix-GAP,
//     output written as bf16 mix [b][co][px] ---
__global__ __launch_bounds__(256) void k_conv(const unsigned short* __restrict__ xt,
                                              const unsigned short* __restrict__ wc,
                                              unsigned short* __restrict__ mixb,
                                              float* __restrict__ cpart) {
    __shared__ unsigned short xs[1600*8];   // 25.6 KB
    __shared__ unsigned short wl[2304*8];   // 36.9 KB
    __shared__ float gsl[4][64];
    int ht = blockIdx.x;
    int cb = blockIdx.y;
    int b  = blockIdx.z;
    int t  = threadIdx.x;
    int wv = t >> 6, lane = t & 63;
    int lr = lane & 15, kq = lane >> 4;
    int h0 = ht * 4;

    const unsigned short* xtb = xt + (size_t)b * 66*66*128;
    const unsigned short* wcb = wc + (size_t)b * 9*256*128;

    f32x4 acc[4][4];
    #pragma unroll
    for (int m = 0; m < 4; ++m)
        #pragma unroll
        for (int n = 0; n < 4; ++n) acc[m][n] = (f32x4){0.f,0.f,0.f,0.f};

    for (int ci0 = 0; ci0 < CIN_; ci0 += 32) {
        __syncthreads();
        for (int j = wv; j < 25; j += 4) {
            int s = j*64 + lane;
            if (s > 1583) s = 1583;
            int pos = s >> 2, q = s & 3;
            int rp = pos / 66, cp = pos - rp*66;
            const unsigned short* g = xtb + (((size_t)(h0 + rp)*66 + cp)*128 + ci0 + q*8);
            gl16(g, (const char*)xs + (size_t)j*1024);
        }
        for (int j = wv; j < 36; j += 4) {
            int s = j*64 + lane;
            int tap = s >> 8, col = (s >> 2) & 63, q = s & 3;
            const unsigned short* g = wcb + (((size_t)tap*COUT_ + cb*64 + col)*128 + ci0 + q*8);
            gl16(g, (const char*)wl + (size_t)j*1024);
        }
        asm volatile("s_waitcnt vmcnt(0)" ::: "memory");
        __syncthreads();

        #pragma unroll
        for (int dh = 0; dh < 3; ++dh) {
            #pragma unroll
            for (int dw = 0; dw < 3; ++dw) {
                int tap = dh*3 + dw;
                short8v af[4], bfv[4];
                #pragma unroll
                for (int m = 0; m < 4; ++m)
                    af[m] = *(const short8v*)(wl + ((size_t)tap*2048 + (m*16 + lr)*32 + kq*8));
                #pragma unroll
                for (int n = 0; n < 4; ++n)
                    bfv[n] = *(const short8v*)(xs + ((size_t)(wv+dh)*2112 + (n*16 + lr + dw)*32 + kq*8));
                #pragma unroll
                for (int m = 0; m < 4; ++m)
                    #pragma unroll
                    for (int n = 0; n < 4; ++n)
                        acc[m][n] = __builtin_amdgcn_mfma_f32_16x16x32_bf16(
                            af[m], bfv[n], acc[m][n], 0, 0, 0);
            }
        }
    }

    // C write (bf16 mix)
    unsigned short* ob = mixb + ((size_t)b*COUT_ + cb*64)*HW_ + (h0 + wv)*W_;
    #pragma unroll
    for (int m = 0; m < 4; ++m)
        #pragma unroll
        for (int n = 0; n < 4; ++n) {
            f32x4 v = acc[m][n];
            #pragma unroll
            for (int r = 0; r < 4; ++r)
                ob[(size_t)(m*16 + kq*4 + r)*HW_ + n*16 + lr] = f2bf(v[r]);
        }

    // fused GAP partials
    float gp[4][4];
    #pragma unroll
    for (int m = 0; m < 4; ++m)
        #pragma unroll
        for (int r = 0; r < 4; ++r)
            gp[m][r] = acc[m][0][r] + acc[m][1][r] + acc[m][2][r] + acc[m][3][r];
    #pragma unroll
    for (int o = 8; o > 0; o >>= 1)
        #pragma unroll
        for (int m = 0; m < 4; ++m)
            #pragma unroll
            for (int r = 0; r < 4; ++r)
                gp[m][r] += __shfl_down(gp[m][r], o, 64);
    if ((lane & 15) == 0) {
        #pragma unroll
        for (int m = 0; m < 4; ++m)
            #pragma unroll
            for (int r = 0; r < 4; ++r)
                gsl[wv][m*16 + kq*4 + r] = gp[m][r];
    }
    __syncthreads();
    if (t < 64) {
        float s = gsl[0][t] + gsl[1][t] + gsl[2][t] + gsl[3][t];
        cpart[((size_t)b*16 + ht)*COUT_ + cb*64 + t] = s;
    }
}

// --- SE channel attention (reduces conv gap partials first) ---
__global__ void k_ca(const float* __restrict__ cpart, const float* ca1w, const float* ca1b,
                     const float* ca2w, const float* ca2b, float* __restrict__ ca) {
    int b = blockIdx.x;
    int t = threadIdx.x;   // 64
    __shared__ float pfull[256];
    __shared__ float h1[64];
    for (int i = t; i < 256; i += 64) {
        float s = 0.f;
        for (int h = 0; h < 16; ++h) s += cpart[((size_t)b*16 + h)*COUT_ + i];
        pfull[i] = s * (1.f/(float)HW_);
    }
    __syncthreads();
    float s = ca1b[t];
    for (int c = 0; c < COUT_; ++c) s += pfull[c] * ca1w[t*COUT_ + c];
    h1[t] = fmaxf(s, 0.f);
    __syncthreads();
    for (int i = 0; i < 4; ++i) {
        int co = t*4 + i;
        float s2 = ca2b[co];
        for (int j = 0; j < 64; ++j) s2 += h1[j] * ca2w[co*64 + j];
        ca[b*COUT_ + co] = 1.f/(1.f + expf(-s2));
    }
}

// --- SA tap-contraction GEMM: u[b][tap][px] = sum_c wsa[tap][c]*mix[b][c][px] ---
__global__ __launch_bounds__(256) void k_sa_gemm(const unsigned short* __restrict__ mixb,
                                                 const unsigned short* __restrict__ wsa,
                                                 float* __restrict__ u) {
    __shared__ unsigned short wl[16384];  // [64 tap][256 c] swizzled (32KB)
    __shared__ unsigned short bt[16384];  // [64 px][256 c] swizzled (32KB)
    int pxt = blockIdx.x;   // 0..63
    int b   = blockIdx.y;
    int t = threadIdx.x, wv = t >> 6, lane = t & 63;
    int lr = lane & 15, kq = lane >> 4;
    int px0 = pxt * 64;

    #pragma unroll
    for (int k = 0; k < 8; ++k) {
        int s = t + k*256;               // 0..2047
        int row = s >> 5, cs = s & 31;
        short8v v = *(const short8v*)(wsa + row*256 + cs*8);
        int off = row*512 + ((cs*16) ^ ((row & 7) << 4));
        *(short8v*)((char*)wl + off) = v;
    }
    {
        int px = lane;
        const unsigned short* mb = mixb + (size_t)b*COUT_*HW_ + px0 + px;
        #pragma unroll
        for (int c8 = 0; c8 < 8; ++c8) {
            int cb = wv*64 + c8*8;
            short8v v;
            #pragma unroll
            for (int j = 0; j < 8; ++j)
                v[j] = (short)mb[(size_t)(cb + j)*HW_];
            int off = px*512 + ((cb*2) ^ ((px & 7) << 4));
            *(short8v*)((char*)bt + off) = v;
        }
    }
    __syncthreads();

    f32x4 acc[4];
    #pragma unroll
    for (int n = 0; n < 4; ++n) acc[n] = (f32x4){0.f,0.f,0.f,0.f};

    #pragma unroll
    for (int ks = 0; ks < 8; ++ks) {
        int ci0 = ks*32;
        int arow = wv*16 + lr;
        short8v a = *(const short8v*)((const char*)wl +
                        arow*512 + (((ci0 + kq*8)*2) ^ ((arow & 7) << 4)));
        #pragma unroll
        for (int n = 0; n < 4; ++n) {
            int prow = n*16 + lr;
            short8v bv = *(const short8v*)((const char*)bt +
                            prow*512 + (((ci0 + kq*8)*2) ^ ((prow & 7) << 4)));
            acc[n] = __builtin_amdgcn_mfma_f32_16x16x32_bf16(a, bv, acc[n], 0, 0, 0);
        }
    }

    float* ub = u + (size_t)b*64*HW_;
    #pragma unroll
    for (int n = 0; n < 4; ++n)
        #pragma unroll
        for (int r = 0; r < 4; ++r)
            ub[(size_t)(wv*16 + kq*4 + r)*HW_ + px0 + n*16 + lr] = acc[n][r];
}

// --- SA tap-shift reduce + sigmoid ---
__global__ void k_sared(const float* __restrict__ u, const float* __restrict__ sab,
                        float* __restrict__ sa) {
    int b = blockIdx.y;
    int h = blockIdx.x * 4 + (threadIdx.x >> 6);
    int w = threadIdx.x & 63;
    float s = sab[0];
    const float* ub = u + (size_t)b*64*HW_;
    #pragma unroll
    for (int dh = 0; dh < 7; ++dh) {
        int hh = h + dh - 3;
        if (hh < 0 || hh >= H_) continue;
        #pragma unroll
        for (int dw = 0; dw < 7; ++dw) {
            int ww = w + dw - 3;
            if (ww < 0 || ww >= W_) continue;
            s += ub[(size_t)(dh*7 + dw)*HW_ + hh*W_ + ww];
        }
    }
    sa[(size_t)b*HW_ + h*W_ + w] = 1.f/(1.f + expf(-s));
}

// --- BN stats over mix*ca*sa (read-only, bf16 mix) ---
__global__ void k_stats(const unsigned short* __restrict__ mixb, const float* __restrict__ ca,
                        const float* __restrict__ sa,
                        float* __restrict__ psum, float* __restrict__ psq) {
    int c = blockIdx.x & 255;
    int b = blockIdx.x >> 8;
    float cav = ca[b*COUT_ + c];
    const unsigned short* pl = mixb + ((size_t)b*COUT_ + c) * HW_;
    const float* sab = sa + (size_t)b * HW_;
    float s = 0.f, sq = 0.f;
    for (int i = threadIdx.x; i < HW_/8; i += 256) {
        short8v v = ((const short8v*)pl)[i];
        float4 w0 = ((const float4*)sab)[2*i];
        float4 w1 = ((const float4*)sab)[2*i+1];
        float f0 = bf2f((unsigned short)v[0])*cav*w0.x;
        float f1 = bf2f((unsigned short)v[1])*cav*w0.y;
        float f2 = bf2f((unsigned short)v[2])*cav*w0.z;
        float f3 = bf2f((unsigned short)v[3])*cav*w0.w;
        float f4 = bf2f((unsigned short)v[4])*cav*w1.x;
        float f5 = bf2f((unsigned short)v[5])*cav*w1.y;
        float f6 = bf2f((unsigned short)v[6])*cav*w1.z;
        float f7 = bf2f((unsigned short)v[7])*cav*w1.w;
        s  += f0+f1+f2+f3+f4+f5+f6+f7;
        sq += f0*f0+f1*f1+f2*f2+f3*f3+f4*f4+f5*f5+f6*f6+f7*f7;
    }
    for (int o = 32; o > 0; o >>= 1) { s += __shfl_down(s,o,64); sq += __shfl_down(sq,o,64); }
    __shared__ float ls[8];
    int wid = threadIdx.x>>6, lane = threadIdx.x&63;
    if (lane==0) { ls[wid]=s; ls[4+wid]=sq; }
    __syncthreads();
    if (threadIdx.x==0) {
        psum[b*COUT_+c] = ls[0]+ls[1]+ls[2]+ls[3];
        psq [b*COUT_+c] = ls[4]+ls[5]+ls[6]+ls[7];
    }
}

// --- finalize BN scale/shift ---
__global__ void k_bnfin(const float* __restrict__ psum, const float* __restrict__ psq,
                        const float* __restrict__ gamma, const float* __restrict__ beta,
                        float* __restrict__ scale, float* __restrict__ shift) {
    int c = threadIdx.x; // 256
    float s=0.f, q=0.f;
    for (int b = 0; b < B_; ++b) { s += psum[b*COUT_+c]; q += psq[b*COUT_+c]; }
    float n = (float)(B_*HW_);
    float mean = s/n;
    float var = q/n - mean*mean;
    float sc = gamma[c] * rsqrtf(var + 1e-5f);
    scale[c] = sc;
    shift[c] = beta[c] - mean*sc;
}

// --- recompute mix*ca*sa from bf16 mix, BN + ReLU -> fp32 d_out ---
__global__ void k_bnapply(const unsigned short* __restrict__ mixb, float* __restrict__ out,
                          const float* __restrict__ ca, const float* __restrict__ sa,
                          const float* __restrict__ scale, const float* __restrict__ shift) {
    size_t i = (size_t)blockIdx.x * 256 + threadIdx.x;   // short8 idx, 2097152 total
    int c = (int)((i >> 9) & 255);
    int b = (int)(i >> 17);
    int px8 = (int)(i & 511);
    float cav = ca[b*COUT_ + c];
    float sc = scale[c], sh = shift[c];
    short8v v = ((const short8v*)mixb)[i];
    const float4* sp = (const float4*)(sa + (size_t)b*HW_) + (size_t)px8*2;
    float4 w0 = sp[0], w1 = sp[1];
    float4 o0, o1;
    o0.x = fmaxf(fmaf(bf2f((unsigned short)v[0])*cav*w0.x, sc, sh), 0.f);
    o0.y = fmaxf(fmaf(bf2f((unsigned short)v[1])*cav*w0.y, sc, sh), 0.f);
    o0.z = fmaxf(fmaf(bf2f((unsigned short)v[2])*cav*w0.z, sc, sh), 0.f);
    o0.w = fmaxf(fmaf(bf2f((unsigned short)v[3])*cav*w0.w, sc, sh), 0.f);
    o1.x = fmaxf(fmaf(bf2f((unsigned short)v[4])*cav*w1.x, sc, sh), 0.f);
    o1.y = fmaxf(fmaf(bf2f((unsigned short)v[5])*cav*w1.y, sc, sh), 0.f);
    o1.z = fmaxf(fmaf(bf2f((unsigned short)v[6])*cav*w1.z, sc, sh), 0.f);
    o1.w = fmaxf(fmaf(bf2f((unsigned short)v[7])*cav*w1.w, sc, sh), 0.f);
    ((float4*)out)[i*2]   = o0;
    ((float4*)out)[i*2+1] = o1;
}

extern "C" void kernel_launch(void* const* d_in, const int* in_sizes, int n_in,
                              void* d_out, int out_size, void* d_ws, size_t ws_size,
                              hipStream_t stream) {
    const float* x    = (const float*)d_in[0];
    const float* ew   = (const float*)d_in[1];
    const float* r1w  = (const float*)d_in[2];
    const float* r1b  = (const float*)d_in[3];
    const float* r2w  = (const float*)d_in[4];
    const float* r2b  = (const float*)d_in[5];
    const float* r3w  = (const float*)d_in[6];
    const float* r3b  = (const float*)d_in[7];
    const float* ca1w = (const float*)d_in[8];
    const float* ca1b = (const float*)d_in[9];
    const float* ca2w = (const float*)d_in[10];
    const float* ca2b = (const float*)d_in[11];
    const float* saw  = (const float*)d_in[12];
    const float* sab  = (const float*)d_in[13];
    const float* gm   = (const float*)d_in[14];
    const float* bt   = (const float*)d_in[15];
    float* out = (float*)d_out;
    float* ws  = (float*)d_ws;
    unsigned short* wcb  = (unsigned short*)(ws + WS_WCB_F);
    unsigned short* xt   = (unsigned short*)(ws + WS_XT_F);
    unsigned short* wsa  = (unsigned short*)(ws + WS_WSA);
    unsigned short* mixb = (unsigned short*)(ws + WS_MIX_F);
    float* u = ws + WS_U_F;   // overlaps xt region (xt dead after k_conv)

    k_xt<<<dim3(64,16), 256, 0, stream>>>(x, xt, ws+WS_GPX);
    k_route<<<16, 128, 0, stream>>>(ws+WS_GPX, r1w, r1b, r2w, r2b, r3w, r3b, ws+WS_RW);
    k_wcomb<<<320, 256, 0, stream>>>(ew, ws+WS_RW, wcb, saw, wsa);
    k_conv<<<dim3(16,4,16), 256, 0, stream>>>(xt, wcb, mixb, ws+WS_CP);
    k_ca<<<B_, 64, 0, stream>>>(ws+WS_CP, ca1w, ca1b, ca2w, ca2b, ws+WS_CA);
    k_sa_gemm<<<dim3(64,16), 256, 0, stream>>>(mixb, wsa, u);
    k_sared<<<dim3(16,16), 256, 0, stream>>>(u, sab, ws+WS_SA);
    k_stats<<<B_*COUT_, 256, 0, stream>>>(mixb, ws+WS_CA, ws+WS_SA, ws+WS_PSUM, ws+WS_PSQ);
    k_bnfin<<<1, 256, 0, stream>>>(ws+WS_PSUM, ws+WS_PSQ, gm, bt, ws+WS_BNSCALE, ws+WS_BNSHIFT);
    k_bnapply<<<8192, 256, 0, stream>>>(mixb, out, ws+WS_CA, ws+WS_SA, ws+WS_BNSCALE, ws+WS_BNSHIFT);
}